// Round 5
// baseline (396.187 us; speedup 1.0000x reference)
//
#include <hip/hip_runtime.h>

#define NN 100000
#define NE 1600000
#define ET (NE + NN)
#define NB 391          // scan blocks of 256 nodes
#define NTILE (NN/16)   // 6250 gemm tiles

typedef _Float16 f16;
typedef __attribute__((ext_vector_type(8))) _Float16 half8;
typedef __attribute__((ext_vector_type(4))) float f32x4;

__device__ __forceinline__ unsigned short hbits(float v){
    f16 h = (f16)v;
    return *(unsigned short*)&h;
}
// pack 2 f32 -> 2 f16 (round-to-zero) in one v_cvt_pk_rtz instruction
__device__ __forceinline__ unsigned pk16(float a, float b){
    auto p = __builtin_amdgcn_cvt_pkrtz(a, b);   // __fp16 ext_vector(2)
    return *(unsigned*)&p;
}
__device__ __forceinline__ float fast_tanh(float x){
    float e = __expf(2.f*x);
    return 1.f - __fdividef(2.f, e + 1.f);
}
// acc_lo += f16(lo half of h2) * a ; acc_hi += f16(hi half of h2) * a
__device__ __forceinline__ void fmix2(float& al, float& ah, unsigned h2, float a){
    asm("v_fma_mix_f32 %0, %2, %3, %0 op_sel_hi:[1,0,0]\n\t"
        "v_fma_mix_f32 %1, %2, %3, %1 op_sel:[1,0,0] op_sel_hi:[1,0,0]"
        : "+v"(al), "+v"(ah) : "v"(h2), "v"(a));
}

// ---------------- CSR build: direct atomic (no buckets) ----------------
// deg: 1.7M fire-and-forget atomics over 100K addrs (mean 17/addr).
__global__ void __launch_bounds__(256) k_deg(const int* __restrict__ dst,
        int* __restrict__ deg){
    int e0 = blockIdx.x*2048 + threadIdx.x;
    #pragma unroll
    for(int k=0;k<8;k++){
        int e = e0 + k*256;
        if(e < ET){
            int d = (e < NE) ? dst[e] : (e - NE);   // tail = self loops
            atomicAdd(&deg[d], 1);
        }
    }
}

// per-256-node block sums
__global__ void __launch_bounds__(256) k_scan1(const int* __restrict__ deg,
        int* __restrict__ bsum){
    __shared__ int red[256];
    int t = threadIdx.x, n = blockIdx.x*256 + t;
    red[t] = (n < NN) ? deg[n] : 0;
    __syncthreads();
    for(int off=128; off>=1; off>>=1){ if(t<off) red[t]+=red[t+off]; __syncthreads(); }
    if(t == 0) bsum[blockIdx.x] = red[0];
}

// exclusive scan of NB block sums (single block, 512 threads)
__global__ void __launch_bounds__(512) k_scan2(int* __restrict__ bsum){
    __shared__ int s[512];
    int t = threadIdx.x;
    int orig = (t < NB) ? bsum[t] : 0;
    s[t] = orig; __syncthreads();
    for(int off=1; off<512; off<<=1){
        int u = (t>=off) ? s[t-off] : 0;
        __syncthreads(); s[t] += u; __syncthreads();
    }
    if(t < NB) bsum[t] = s[t] - orig;
}

// per-node exclusive scan + base -> rowst, cursor copy
__global__ void __launch_bounds__(256) k_scan3(const int* __restrict__ deg,
        const int* __restrict__ bsum, int* __restrict__ rowst,
        int* __restrict__ cur){
    __shared__ int ls[256];
    int t = threadIdx.x, n = blockIdx.x*256 + t;
    int v = (n < NN) ? deg[n] : 0;
    ls[t] = v; __syncthreads();
    for(int off=1; off<256; off<<=1){
        int u = (t>=off) ? ls[t-off] : 0;
        __syncthreads(); ls[t] += u; __syncthreads();
    }
    int r = bsum[blockIdx.x] + ls[t] - v;
    if(n < NN){ rowst[n] = r; cur[n] = r; }
}

// scatter: absolute slot via per-node cursor atomic (returns), write src id
__global__ void __launch_bounds__(256) k_scatter(const int* __restrict__ src,
        const int* __restrict__ dst, int* __restrict__ cur,
        int* __restrict__ edge_src){
    int e0 = blockIdx.x*2048 + threadIdx.x;
    #pragma unroll
    for(int k=0;k<8;k++){
        int e = e0 + k*256;
        if(e < ET){
            int s, d;
            if(e < NE){ s = src[e]; d = dst[e]; } else { s = e - NE; d = s; }
            int pos = atomicAdd(&cur[d], 1);
            edge_src[pos] = s;
        }
    }
}

// ---------------- h = x@W via f16 MFMA, s_src, s_dst ----------------
template<int FPIN>
__global__ void __launch_bounds__(256) k_gemm(const void* __restrict__ xin,
        const float* __restrict__ W, const float* __restrict__ avs,
        const float* __restrict__ avd, f16* __restrict__ hb,
        float* __restrict__ ssrc, float* __restrict__ sdst){
    int tid = threadIdx.x, lane = tid & 63;
    int col = lane & 15, q = lane >> 4;
    half8 Bf[2][4];
    #pragma unroll
    for(int kh=0;kh<2;kh++){
        #pragma unroll
        for(int nb=0;nb<4;nb++){
            half8 b;
            #pragma unroll
            for(int j=0;j<8;j++){
                float w = W[(kh*32 + q*8 + j)*64 + nb*16 + col];
                b[j] = (f16)w;
            }
            Bf[kh][nb] = b;
        }
    }
    float as[4], ad[4];
    #pragma unroll
    for(int nb=0;nb<4;nb++){ as[nb] = avs[nb*16+col]; ad[nb] = avd[nb*16+col]; }

    int gw = (blockIdx.x*256 + tid) >> 6;
    int nwaves = gridDim.x*4;
    for(int tile = gw; tile < NTILE; tile += nwaves){
        int n0 = tile*16;
        f32x4 acc[4];
        #pragma unroll
        for(int nb=0;nb<4;nb++) acc[nb] = (f32x4){0.f,0.f,0.f,0.f};
        #pragma unroll
        for(int kh=0;kh<2;kh++){
            half8 a;
            if(FPIN){
                const float4* xr = (const float4*)((const float*)xin
                                    + (size_t)(n0+col)*64 + kh*32 + q*8);
                float4 u = xr[0], v = xr[1];
                union { half8 h; uint4 u4; } A;
                A.u4.x = pk16(u.x, u.y);
                A.u4.y = pk16(u.z, u.w);
                A.u4.z = pk16(v.x, v.y);
                A.u4.w = pk16(v.z, v.w);
                a = A.h;
            } else {
                a = *(const half8*)((const f16*)xin
                                    + (size_t)(n0+col)*64 + kh*32 + q*8);
            }
            #pragma unroll
            for(int nb=0;nb<4;nb++)
                acc[nb] = __builtin_amdgcn_mfma_f32_16x16x32_f16(a, Bf[kh][nb], acc[nb], 0,0,0);
        }
        #pragma unroll
        for(int nb=0;nb<4;nb++){
            #pragma unroll
            for(int r=0;r<4;r++)
                hb[(size_t)(n0 + q*4 + r)*64 + nb*16 + col] = (f16)acc[nb][r];
        }
        #pragma unroll
        for(int r=0;r<4;r++){
            float ps = acc[0][r]*as[0] + acc[1][r]*as[1] + acc[2][r]*as[2] + acc[3][r]*as[3];
            float pd = acc[0][r]*ad[0] + acc[1][r]*ad[1] + acc[2][r]*ad[2] + acc[3][r]*ad[3];
            #pragma unroll
            for(int m=8;m>=1;m>>=1){ ps += __shfl_xor(ps,m); pd += __shfl_xor(pd,m); }
            if(col == 0){ ssrc[n0 + q*4 + r] = ps; sdst[n0 + q*4 + r] = pd; }
        }
    }
}

// ---------------- full-wave fallback: one node, any degree ----------------
template<int LAYER>
__device__ __forceinline__ void node_full(int node, int lane, int2* lp,
        const int* __restrict__ rowst, const int* __restrict__ deg,
        const int* __restrict__ edge_src, const float* __restrict__ ssrc,
        const float* __restrict__ sdst, const f16* __restrict__ hb,
        const float* __restrict__ bias, const float* __restrict__ Wl,
        const float* __restrict__ bl, f16* __restrict__ out1b,
        float* __restrict__ outF){
    int rs = rowst[node];
    int d  = deg[node];
    float sd = sdst[node];
    int g8 = lane >> 3;
    int c  = lane & 7;
    float a0=0.f,a1=0.f,a2=0.f,a3=0.f,a4=0.f,a5=0.f,a6=0.f,a7=0.f;

    float lmax = -1e30f;
    for(int j=lane; j<d; j+=64){
        int sj = edge_src[rs+j];
        float t = ssrc[sj] + sd;
        lmax = fmaxf(lmax, fmaxf(t, 0.2f*t));
    }
    #pragma unroll
    for(int m=32;m>=1;m>>=1) lmax = fmaxf(lmax, __shfl_xor(lmax,m));
    float lsum = 0.f;
    for(int j=lane; j<d; j+=64){
        int sj = edge_src[rs+j];
        float t = ssrc[sj] + sd;
        lsum += __expf(fmaxf(t, 0.2f*t) - lmax);
    }
    #pragma unroll
    for(int m=32;m>=1;m>>=1) lsum += __shfl_xor(lsum,m);
    float inv = 1.0f/(lsum + 1e-16f);
    for(int cb=0; cb<d; cb+=64){
        int s2 = 0; float al = 0.f;
        int j = cb + lane;
        if(j < d){
            s2 = edge_src[rs+j];
            float t = ssrc[s2] + sd;
            al = __expf(fmaxf(t, 0.2f*t) - lmax) * inv;
        }
        lp[lane] = make_int2(__float_as_int(al), s2);
        int dd = min(d - cb, 64);
        for(int i0=0; i0<dd; i0+=16){
            int2 e0 = lp[i0 + g8];
            int2 e1 = lp[i0 + 8 + g8];
            float f0 = __int_as_float(e0.x);
            float f1 = __int_as_float(e1.x);
            uint4 k0 = *(const uint4*)(hb + ((size_t)e0.y<<6) + (c<<3));
            uint4 k1 = *(const uint4*)(hb + ((size_t)e1.y<<6) + (c<<3));
            fmix2(a0,a1,k0.x,f0); fmix2(a2,a3,k0.y,f0);
            fmix2(a4,a5,k0.z,f0); fmix2(a6,a7,k0.w,f0);
            fmix2(a0,a1,k1.x,f1); fmix2(a2,a3,k1.y,f1);
            fmix2(a4,a5,k1.z,f1); fmix2(a6,a7,k1.w,f1);
        }
    }
    #pragma unroll
    for(int m=32;m>=8;m>>=1){
        a0 += __shfl_xor(a0,m); a1 += __shfl_xor(a1,m);
        a2 += __shfl_xor(a2,m); a3 += __shfl_xor(a3,m);
        a4 += __shfl_xor(a4,m); a5 += __shfl_xor(a5,m);
        a6 += __shfl_xor(a6,m); a7 += __shfl_xor(a7,m);
    }
    const float4* bp = (const float4*)bias;
    float4 bv0 = bp[c*2], bv1 = bp[c*2+1];
    if(LAYER == 1){
        if(g8 == 0){
            uint4 o;
            o.x = (unsigned)hbits(fast_tanh(a0+bv0.x)) | ((unsigned)hbits(fast_tanh(a1+bv0.y))<<16);
            o.y = (unsigned)hbits(fast_tanh(a2+bv0.z)) | ((unsigned)hbits(fast_tanh(a3+bv0.w))<<16);
            o.z = (unsigned)hbits(fast_tanh(a4+bv1.x)) | ((unsigned)hbits(fast_tanh(a5+bv1.y))<<16);
            o.w = (unsigned)hbits(fast_tanh(a6+bv1.z)) | ((unsigned)hbits(fast_tanh(a7+bv1.w))<<16);
            *(uint4*)(out1b + ((size_t)node<<6) + (c<<3)) = o;
        }
    } else {
        const float4* wp = (const float4*)Wl;
        float4 wv0 = wp[c*2], wv1 = wp[c*2+1];
        float r = (a0+bv0.x)*wv0.x + (a1+bv0.y)*wv0.y + (a2+bv0.z)*wv0.z + (a3+bv0.w)*wv0.w
                + (a4+bv1.x)*wv1.x + (a5+bv1.y)*wv1.y + (a6+bv1.z)*wv1.z + (a7+bv1.w)*wv1.w;
        r += __shfl_xor(r,1); r += __shfl_xor(r,2); r += __shfl_xor(r,4);
        if(lane == 0) outF[node] = r + bl[0];
    }
}

// ---------------- attention + aggregation: 2 nodes per wave ----------------
template<int LAYER>
__global__ void __launch_bounds__(256) k_agg(
        const int* __restrict__ rowst, const int* __restrict__ deg,
        const int* __restrict__ edge_src,
        const float* __restrict__ ssrc, const float* __restrict__ sdst,
        const f16* __restrict__ hb,
        const float* __restrict__ bias, const float* __restrict__ Wl,
        const float* __restrict__ bl,
        f16* __restrict__ out1b, float* __restrict__ outF){
    __shared__ int2 pairs[256];
    int tid = threadIdx.x;
    int wv   = (blockIdx.x*256 + tid) >> 6;   // wave id: 0..NN/2-1
    int lane = tid & 63;
    if(wv*2 >= NN) return;
    int2* lp = pairs + (tid & 192);           // wave-private 64-entry table
    int half = lane >> 5, l = lane & 31;
    int node = wv*2 + half;

    int rs = rowst[node];
    int d  = deg[node];
    float sd = sdst[node];
    int dmax = max(d, __shfl_xor(d, 32));

    if(dmax <= 32){
        // ---- per-half softmax ----
        int s = 0; float pr = 0.f;
        if(l < d){
            s = edge_src[rs + l];
            float t = ssrc[s] + sd;
            t = fmaxf(t, 0.2f*t);            // leaky_relu
            pr = __expf(fminf(t, 80.f));     // no max-shift: logits O(10)
        }
        float sm = pr;
        #pragma unroll
        for(int m=16;m>=1;m>>=1) sm += __shfl_xor(sm,m);
        float alpha = pr * (1.0f/(sm + 1e-16f));
        lp[lane] = make_int2(__float_as_int(alpha), s);   // lane = half*32+l

        // ---- gather: 8 edges/iter per half ----
        int g4 = l >> 3;                     // row-group 0..3
        int c  = l & 7;                      // channel chunk
        int base = half << 5;
        float a0=0.f,a1=0.f,a2=0.f,a3=0.f,a4=0.f,a5=0.f,a6=0.f,a7=0.f;
        for(int i0=0; i0<d; i0+=8){
            int2 e0 = lp[base + i0 + g4];
            int2 e1 = lp[base + i0 + 4 + g4];
            float f0 = __int_as_float(e0.x);
            float f1 = __int_as_float(e1.x);
            uint4 k0 = *(const uint4*)(hb + ((size_t)e0.y<<6) + (c<<3));
            uint4 k1 = *(const uint4*)(hb + ((size_t)e1.y<<6) + (c<<3));
            fmix2(a0,a1,k0.x,f0); fmix2(a2,a3,k0.y,f0);
            fmix2(a4,a5,k0.z,f0); fmix2(a6,a7,k0.w,f0);
            fmix2(a0,a1,k1.x,f1); fmix2(a2,a3,k1.y,f1);
            fmix2(a4,a5,k1.z,f1); fmix2(a6,a7,k1.w,f1);
        }

        // ---- channel-splitting fold over row-groups (lane bits 3,4) ----
        bool b3 = (l >> 3) & 1, b4 = (l >> 4) & 1;
        float u0 = b3 ? a4 : a0, v0 = b3 ? a0 : a4; u0 += __shfl_xor(v0, 8);
        float u1 = b3 ? a5 : a1, v1 = b3 ? a1 : a5; u1 += __shfl_xor(v1, 8);
        float u2 = b3 ? a6 : a2, v2 = b3 ? a2 : a6; u2 += __shfl_xor(v2, 8);
        float u3 = b3 ? a7 : a3, v3 = b3 ? a3 : a7; u3 += __shfl_xor(v3, 8);
        float w0 = b4 ? u2 : u0, z0 = b4 ? u0 : u2; w0 += __shfl_xor(z0, 16);
        float w1 = b4 ? u3 : u1, z1 = b4 ? u1 : u3; w1 += __shfl_xor(z1, 16);
        int ch0 = (c<<3) + ((int)b3<<2) + ((int)b4<<1);   // even; w1 = ch0+1

        if(LAYER == 1){
            float2 bv = ((const float2*)bias)[ch0>>1];
            unsigned o = pk16(fast_tanh(w0 + bv.x), fast_tanh(w1 + bv.y));
            *(unsigned*)(out1b + ((size_t)node<<6) + ch0) = o;
        } else {
            float2 bv = ((const float2*)bias)[ch0>>1];
            float2 wl = ((const float2*)Wl)[ch0>>1];
            float r = (w0 + bv.x)*wl.x + (w1 + bv.y)*wl.y;
            #pragma unroll
            for(int m=16;m>=1;m>>=1) r += __shfl_xor(r,m);
            if(l == 0) outF[node] = r + bl[0];
        }
    } else {
        // rare: a node with d>32 in this pair -> full-wave generic, twice
        node_full<LAYER>(wv*2,   lane, lp, rowst, deg, edge_src, ssrc, sdst,
                         hb, bias, Wl, bl, out1b, outF);
        node_full<LAYER>(wv*2+1, lane, lp, rowst, deg, edge_src, ssrc, sdst,
                         hb, bias, Wl, bl, out1b, outF);
    }
}

// ---------------- launch ----------------
extern "C" void kernel_launch(void* const* d_in, const int* in_sizes, int n_in,
                              void* d_out, int out_size, void* d_ws, size_t ws_size,
                              hipStream_t stream) {
    const float* x   = (const float*)d_in[0];
    const int*   ei  = (const int*)d_in[1];
    const float* W1  = (const float*)d_in[2];
    const float* as1 = (const float*)d_in[3];
    const float* ad1 = (const float*)d_in[4];
    const float* b1  = (const float*)d_in[5];
    const float* W2  = (const float*)d_in[6];
    const float* as2 = (const float*)d_in[7];
    const float* ad2 = (const float*)d_in[8];
    const float* b2  = (const float*)d_in[9];
    const float* Wl  = (const float*)d_in[10];
    const float* bl  = (const float*)d_in[11];
    float* out = (float*)d_out;

    const int* srcp = ei;
    const int* dstp = ei + NE;

    char* w = (char*)d_ws;
    int*   edge_src = (int*)w;  w += (size_t)ET*4;      //  6.8 MB
    f16*   hb       = (f16*)w;  w += (size_t)NN*64*2;   // 12.8 MB
    f16*   t1b      = (f16*)w;  w += (size_t)NN*64*2;   // 12.8 MB
    int*   rowst    = (int*)w;  w += (size_t)NN*4;
    int*   deg      = (int*)w;  w += (size_t)NN*4;
    float* ssrc     = (float*)w; w += (size_t)NN*4;
    float* sdst     = (float*)w; w += (size_t)NN*4;
    int*   cur      = (int*)w;  w += (size_t)NN*4;
    int*   bsum     = (int*)w;  w += (size_t)512*4;

    const int nbE = (ET + 2047)/2048;       // 831: 8 edges/thread
    const int nbG = 782;                    // 3128 waves -> ~2 tiles each
    const int nbA = (NN/2 + 3)/4;           // 12500: 4 waves/block, 2 nodes/wave

    (void)hipMemsetAsync(deg, 0, (size_t)NN*4, stream);
    k_deg    <<<nbE, 256, 0, stream>>>(dstp, deg);
    k_scan1  <<<NB,  256, 0, stream>>>(deg, bsum);
    k_scan2  <<<1,   512, 0, stream>>>(bsum);
    k_scan3  <<<NB,  256, 0, stream>>>(deg, bsum, rowst, cur);
    k_scatter<<<nbE, 256, 0, stream>>>(srcp, dstp, cur, edge_src);

    // layer 1
    k_gemm<1><<<nbG, 256, 0, stream>>>((const void*)x, W1, as1, ad1, hb, ssrc, sdst);
    k_agg<1><<<nbA, 256, 0, stream>>>(rowst, deg, edge_src, ssrc, sdst, hb,
                                      b1, (const float*)nullptr, (const float*)nullptr,
                                      t1b, (float*)nullptr);
    // layer 2 + final linear
    k_gemm<0><<<nbG, 256, 0, stream>>>((const void*)t1b, W2, as2, ad2, hb, ssrc, sdst);
    k_agg<2><<<nbA, 256, 0, stream>>>(rowst, deg, edge_src, ssrc, sdst, hb,
                                      b2, Wl, bl,
                                      (f16*)nullptr, out);
}

// Round 6
// 248.363 us; speedup vs baseline: 1.5952x; 1.5952x over previous
//
#include <hip/hip_runtime.h>

#define NN 100000
#define NE 1600000
#define ET (NE + NN)
#define NB 391          // buckets of 256 dst nodes
#define CAP 5120        // slots/bucket (mean 4352, +12 sigma)
#define BST 16          // bcnt pad: 64B per counter
#define NBIN 128        // persistent k_bin blocks: short atomic chain, long runs
#define NTILE (NN/16)   // 6250 gemm tiles

typedef _Float16 f16;
typedef __attribute__((ext_vector_type(8))) _Float16 half8;
typedef __attribute__((ext_vector_type(4))) float f32x4;

__device__ __forceinline__ unsigned short hbits(float v){
    f16 h = (f16)v;
    return *(unsigned short*)&h;
}
// pack 2 f32 -> 2 f16 (round-to-zero) in one v_cvt_pk_rtz instruction
__device__ __forceinline__ unsigned pk16(float a, float b){
    auto p = __builtin_amdgcn_cvt_pkrtz(a, b);   // __fp16 ext_vector(2)
    return *(unsigned*)&p;
}
__device__ __forceinline__ float fast_tanh(float x){
    float e = __expf(2.f*x);
    return 1.f - __fdividef(2.f, e + 1.f);
}
// acc_lo += f16(lo half of h2) * a ; acc_hi += f16(hi half of h2) * a
__device__ __forceinline__ void fmix2(float& al, float& ah, unsigned h2, float a){
    asm("v_fma_mix_f32 %0, %2, %3, %0 op_sel_hi:[1,0,0]\n\t"
        "v_fma_mix_f32 %1, %2, %3, %1 op_sel:[1,0,0] op_sel_hi:[1,0,0]"
        : "+v"(al), "+v"(ah) : "v"(h2), "v"(a));
}

// ---------------- CSR build: bin by dst>>8, persistent blocks ----------------
// NBIN blocks: reservation chain depth 128 (was 831), and each block owns
// ~34 consecutive slots per bucket -> sequential binbuf runs (low write amp).
__global__ void __launch_bounds__(256) k_bin(const int* __restrict__ src,
        const int* __restrict__ dst, int* __restrict__ bcnt,
        int* __restrict__ binbuf){
    __shared__ int cnt[NB];
    __shared__ int cur[NB];
    int t = threadIdx.x;
    for(int i=t;i<NB;i+=256) cnt[i]=0;
    __syncthreads();
    // phase 1: LDS histogram of this block's strided edges
    #pragma unroll 8
    for(int e = blockIdx.x*256 + t; e < ET; e += NBIN*256){
        int d = (e < NE) ? dst[e] : (e - NE);
        atomicAdd(&cnt[d>>8], 1);
    }
    __syncthreads();
    // phase 2: one global reservation per bucket (chain depth = NBIN)
    for(int i=t;i<NB;i+=256){ int c=cnt[i]; cur[i] = c ? atomicAdd(&bcnt[i*BST], c) : 0; }
    __syncthreads();
    // phase 3: scatter into reserved runs
    #pragma unroll 8
    for(int e = blockIdx.x*256 + t; e < ET; e += NBIN*256){
        int s, d;
        if(e < NE){ s = src[e]; d = dst[e]; } else { s = e - NE; d = s; }
        int b = d >> 8;
        int pos = atomicAdd(&cur[b], 1);
        if(pos < CAP) binbuf[b*CAP + pos] = (s << 8) | (d & 255);
    }
}

// ---------------- CSR build: per-bucket dense build (base prefix fused) ----------------
__global__ void __launch_bounds__(256) k_build(const int* __restrict__ bcnt,
        const int* __restrict__ binbuf, int* __restrict__ edge_src,
        int* __restrict__ rowst, int* __restrict__ deg){
    __shared__ int lsrc[CAP];
    __shared__ int ldeg[256], lscan[256], lcur[256], red[256];
    int b = blockIdx.x, t = threadIdx.x;
    int cnt = min(bcnt[b*BST], CAP);
    int part = 0;
    for(int i=t;i<b;i+=256) part += min(bcnt[i*BST], CAP);
    red[t] = part; __syncthreads();
    for(int off=128; off>=1; off>>=1){ if(t<off) red[t]+=red[t+off]; __syncthreads(); }
    int base = red[0];
    __syncthreads();
    ldeg[t] = 0; __syncthreads();
    const int* bb = binbuf + b*CAP;
    for(int i=t;i<cnt;i+=256) atomicAdd(&ldeg[bb[i] & 255], 1);
    __syncthreads();
    int dv = ldeg[t]; lscan[t] = dv; __syncthreads();
    for(int off=1; off<256; off<<=1){
        int u = (t>=off) ? lscan[t-off] : 0;
        __syncthreads(); lscan[t] += u; __syncthreads();
    }
    int excl = lscan[t] - dv; lcur[t] = excl;
    int node = b*256 + t;
    if(node < NN){ rowst[node] = base + excl; deg[node] = dv; }
    __syncthreads();
    for(int i=t;i<cnt;i+=256){
        int ent = bb[i];
        int pos = atomicAdd(&lcur[ent & 255], 1);
        lsrc[pos] = ent >> 8;
    }
    __syncthreads();
    for(int i=t;i<cnt;i+=256) edge_src[base+i] = lsrc[i];
}

// ---------------- h = x@W via f16 MFMA, s_src, s_dst ----------------
template<int FPIN>
__global__ void __launch_bounds__(256) k_gemm(const void* __restrict__ xin,
        const float* __restrict__ W, const float* __restrict__ avs,
        const float* __restrict__ avd, f16* __restrict__ hb,
        float* __restrict__ ssrc, float* __restrict__ sdst){
    int tid = threadIdx.x, lane = tid & 63;
    int col = lane & 15, q = lane >> 4;
    half8 Bf[2][4];
    #pragma unroll
    for(int kh=0;kh<2;kh++){
        #pragma unroll
        for(int nb=0;nb<4;nb++){
            half8 b;
            #pragma unroll
            for(int j=0;j<8;j++){
                float w = W[(kh*32 + q*8 + j)*64 + nb*16 + col];
                b[j] = (f16)w;
            }
            Bf[kh][nb] = b;
        }
    }
    float as[4], ad[4];
    #pragma unroll
    for(int nb=0;nb<4;nb++){ as[nb] = avs[nb*16+col]; ad[nb] = avd[nb*16+col]; }

    int gw = (blockIdx.x*256 + tid) >> 6;
    int nwaves = gridDim.x*4;
    for(int tile = gw; tile < NTILE; tile += nwaves){
        int n0 = tile*16;
        f32x4 acc[4];
        #pragma unroll
        for(int nb=0;nb<4;nb++) acc[nb] = (f32x4){0.f,0.f,0.f,0.f};
        #pragma unroll
        for(int kh=0;kh<2;kh++){
            half8 a;
            if(FPIN){
                const float4* xr = (const float4*)((const float*)xin
                                    + (size_t)(n0+col)*64 + kh*32 + q*8);
                float4 u = xr[0], v = xr[1];
                union { half8 h; uint4 u4; } A;
                A.u4.x = pk16(u.x, u.y);
                A.u4.y = pk16(u.z, u.w);
                A.u4.z = pk16(v.x, v.y);
                A.u4.w = pk16(v.z, v.w);
                a = A.h;
            } else {
                a = *(const half8*)((const f16*)xin
                                    + (size_t)(n0+col)*64 + kh*32 + q*8);
            }
            #pragma unroll
            for(int nb=0;nb<4;nb++)
                acc[nb] = __builtin_amdgcn_mfma_f32_16x16x32_f16(a, Bf[kh][nb], acc[nb], 0,0,0);
        }
        #pragma unroll
        for(int nb=0;nb<4;nb++){
            #pragma unroll
            for(int r=0;r<4;r++)
                hb[(size_t)(n0 + q*4 + r)*64 + nb*16 + col] = (f16)acc[nb][r];
        }
        #pragma unroll
        for(int r=0;r<4;r++){
            float ps = acc[0][r]*as[0] + acc[1][r]*as[1] + acc[2][r]*as[2] + acc[3][r]*as[3];
            float pd = acc[0][r]*ad[0] + acc[1][r]*ad[1] + acc[2][r]*ad[2] + acc[3][r]*ad[3];
            #pragma unroll
            for(int m=8;m>=1;m>>=1){ ps += __shfl_xor(ps,m); pd += __shfl_xor(pd,m); }
            if(col == 0){ ssrc[n0 + q*4 + r] = ps; sdst[n0 + q*4 + r] = pd; }
        }
    }
}

// ---------------- full-wave fallback: one node, any degree ----------------
template<int LAYER>
__device__ __forceinline__ void node_full(int node, int lane, int2* lp,
        const int* __restrict__ rowst, const int* __restrict__ deg,
        const int* __restrict__ edge_src, const float* __restrict__ ssrc,
        const float* __restrict__ sdst, const f16* __restrict__ hb,
        const float* __restrict__ bias, const float* __restrict__ Wl,
        const float* __restrict__ bl, f16* __restrict__ out1b,
        float* __restrict__ outF){
    int rs = rowst[node];
    int d  = deg[node];
    float sd = sdst[node];
    int g8 = lane >> 3;
    int c  = lane & 7;
    float a0=0.f,a1=0.f,a2=0.f,a3=0.f,a4=0.f,a5=0.f,a6=0.f,a7=0.f;

    float lmax = -1e30f;
    for(int j=lane; j<d; j+=64){
        int sj = edge_src[rs+j];
        float t = ssrc[sj] + sd;
        lmax = fmaxf(lmax, fmaxf(t, 0.2f*t));
    }
    #pragma unroll
    for(int m=32;m>=1;m>>=1) lmax = fmaxf(lmax, __shfl_xor(lmax,m));
    float lsum = 0.f;
    for(int j=lane; j<d; j+=64){
        int sj = edge_src[rs+j];
        float t = ssrc[sj] + sd;
        lsum += __expf(fmaxf(t, 0.2f*t) - lmax);
    }
    #pragma unroll
    for(int m=32;m>=1;m>>=1) lsum += __shfl_xor(lsum,m);
    float inv = 1.0f/(lsum + 1e-16f);
    for(int cb=0; cb<d; cb+=64){
        int s2 = 0; float al = 0.f;
        int j = cb + lane;
        if(j < d){
            s2 = edge_src[rs+j];
            float t = ssrc[s2] + sd;
            al = __expf(fmaxf(t, 0.2f*t) - lmax) * inv;
        }
        lp[lane] = make_int2(__float_as_int(al), s2);
        int dd = min(d - cb, 64);
        for(int i0=0; i0<dd; i0+=16){
            int2 e0 = lp[i0 + g8];
            int2 e1 = lp[i0 + 8 + g8];
            float f0 = __int_as_float(e0.x);
            float f1 = __int_as_float(e1.x);
            uint4 k0 = *(const uint4*)(hb + ((size_t)e0.y<<6) + (c<<3));
            uint4 k1 = *(const uint4*)(hb + ((size_t)e1.y<<6) + (c<<3));
            fmix2(a0,a1,k0.x,f0); fmix2(a2,a3,k0.y,f0);
            fmix2(a4,a5,k0.z,f0); fmix2(a6,a7,k0.w,f0);
            fmix2(a0,a1,k1.x,f1); fmix2(a2,a3,k1.y,f1);
            fmix2(a4,a5,k1.z,f1); fmix2(a6,a7,k1.w,f1);
        }
    }
    #pragma unroll
    for(int m=32;m>=8;m>>=1){
        a0 += __shfl_xor(a0,m); a1 += __shfl_xor(a1,m);
        a2 += __shfl_xor(a2,m); a3 += __shfl_xor(a3,m);
        a4 += __shfl_xor(a4,m); a5 += __shfl_xor(a5,m);
        a6 += __shfl_xor(a6,m); a7 += __shfl_xor(a7,m);
    }
    const float4* bp = (const float4*)bias;
    float4 bv0 = bp[c*2], bv1 = bp[c*2+1];
    if(LAYER == 1){
        if(g8 == 0){
            uint4 o;
            o.x = (unsigned)hbits(fast_tanh(a0+bv0.x)) | ((unsigned)hbits(fast_tanh(a1+bv0.y))<<16);
            o.y = (unsigned)hbits(fast_tanh(a2+bv0.z)) | ((unsigned)hbits(fast_tanh(a3+bv0.w))<<16);
            o.z = (unsigned)hbits(fast_tanh(a4+bv1.x)) | ((unsigned)hbits(fast_tanh(a5+bv1.y))<<16);
            o.w = (unsigned)hbits(fast_tanh(a6+bv1.z)) | ((unsigned)hbits(fast_tanh(a7+bv1.w))<<16);
            *(uint4*)(out1b + ((size_t)node<<6) + (c<<3)) = o;
        }
    } else {
        const float4* wp = (const float4*)Wl;
        float4 wv0 = wp[c*2], wv1 = wp[c*2+1];
        float r = (a0+bv0.x)*wv0.x + (a1+bv0.y)*wv0.y + (a2+bv0.z)*wv0.z + (a3+bv0.w)*wv0.w
                + (a4+bv1.x)*wv1.x + (a5+bv1.y)*wv1.y + (a6+bv1.z)*wv1.z + (a7+bv1.w)*wv1.w;
        r += __shfl_xor(r,1); r += __shfl_xor(r,2); r += __shfl_xor(r,4);
        if(lane == 0) outF[node] = r + bl[0];
    }
}

// ---------------- attention + aggregation: 2 nodes per wave ----------------
template<int LAYER>
__global__ void __launch_bounds__(256) k_agg(
        const int* __restrict__ rowst, const int* __restrict__ deg,
        const int* __restrict__ edge_src,
        const float* __restrict__ ssrc, const float* __restrict__ sdst,
        const f16* __restrict__ hb,
        const float* __restrict__ bias, const float* __restrict__ Wl,
        const float* __restrict__ bl,
        f16* __restrict__ out1b, float* __restrict__ outF){
    __shared__ int2 pairs[256];
    int tid = threadIdx.x;
    int wv   = (blockIdx.x*256 + tid) >> 6;   // wave id: 0..NN/2-1
    int lane = tid & 63;
    if(wv*2 >= NN) return;
    int2* lp = pairs + (tid & 192);           // wave-private 64-entry table
    int half = lane >> 5, l = lane & 31;
    int node = wv*2 + half;

    int rs = rowst[node];
    int d  = deg[node];
    float sd = sdst[node];
    int dmax = max(d, __shfl_xor(d, 32));

    if(dmax <= 32){
        // ---- per-half softmax ----
        int s = 0; float pr = 0.f;
        if(l < d){
            s = edge_src[rs + l];
            float t = ssrc[s] + sd;
            t = fmaxf(t, 0.2f*t);            // leaky_relu
            pr = __expf(fminf(t, 80.f));     // no max-shift: logits O(10)
        }
        float sm = pr;
        #pragma unroll
        for(int m=16;m>=1;m>>=1) sm += __shfl_xor(sm,m);
        float alpha = pr * (1.0f/(sm + 1e-16f));
        lp[lane] = make_int2(__float_as_int(alpha), s);   // lane = half*32+l

        // ---- gather: 8 edges/iter per half ----
        int g4 = l >> 3;                     // row-group 0..3
        int c  = l & 7;                      // channel chunk
        int base = half << 5;
        float a0=0.f,a1=0.f,a2=0.f,a3=0.f,a4=0.f,a5=0.f,a6=0.f,a7=0.f;
        for(int i0=0; i0<d; i0+=8){
            int2 e0 = lp[base + i0 + g4];
            int2 e1 = lp[base + i0 + 4 + g4];
            float f0 = __int_as_float(e0.x);
            float f1 = __int_as_float(e1.x);
            uint4 k0 = *(const uint4*)(hb + ((size_t)e0.y<<6) + (c<<3));
            uint4 k1 = *(const uint4*)(hb + ((size_t)e1.y<<6) + (c<<3));
            fmix2(a0,a1,k0.x,f0); fmix2(a2,a3,k0.y,f0);
            fmix2(a4,a5,k0.z,f0); fmix2(a6,a7,k0.w,f0);
            fmix2(a0,a1,k1.x,f1); fmix2(a2,a3,k1.y,f1);
            fmix2(a4,a5,k1.z,f1); fmix2(a6,a7,k1.w,f1);
        }

        // ---- channel-splitting fold over row-groups (lane bits 3,4) ----
        bool b3 = (l >> 3) & 1, b4 = (l >> 4) & 1;
        float u0 = b3 ? a4 : a0, v0 = b3 ? a0 : a4; u0 += __shfl_xor(v0, 8);
        float u1 = b3 ? a5 : a1, v1 = b3 ? a1 : a5; u1 += __shfl_xor(v1, 8);
        float u2 = b3 ? a6 : a2, v2 = b3 ? a2 : a6; u2 += __shfl_xor(v2, 8);
        float u3 = b3 ? a7 : a3, v3 = b3 ? a3 : a7; u3 += __shfl_xor(v3, 8);
        float w0 = b4 ? u2 : u0, z0 = b4 ? u0 : u2; w0 += __shfl_xor(z0, 16);
        float w1 = b4 ? u3 : u1, z1 = b4 ? u1 : u3; w1 += __shfl_xor(z1, 16);
        int ch0 = (c<<3) + ((int)b3<<2) + ((int)b4<<1);   // even; w1 = ch0+1

        if(LAYER == 1){
            float2 bv = ((const float2*)bias)[ch0>>1];
            unsigned o = pk16(fast_tanh(w0 + bv.x), fast_tanh(w1 + bv.y));
            *(unsigned*)(out1b + ((size_t)node<<6) + ch0) = o;
        } else {
            float2 bv = ((const float2*)bias)[ch0>>1];
            float2 wl = ((const float2*)Wl)[ch0>>1];
            float r = (w0 + bv.x)*wl.x + (w1 + bv.y)*wl.y;
            #pragma unroll
            for(int m=16;m>=1;m>>=1) r += __shfl_xor(r,m);
            if(l == 0) outF[node] = r + bl[0];
        }
    } else {
        // rare: a node with d>32 in this pair -> full-wave generic, twice
        node_full<LAYER>(wv*2,   lane, lp, rowst, deg, edge_src, ssrc, sdst,
                         hb, bias, Wl, bl, out1b, outF);
        node_full<LAYER>(wv*2+1, lane, lp, rowst, deg, edge_src, ssrc, sdst,
                         hb, bias, Wl, bl, out1b, outF);
    }
}

// ---------------- launch ----------------
extern "C" void kernel_launch(void* const* d_in, const int* in_sizes, int n_in,
                              void* d_out, int out_size, void* d_ws, size_t ws_size,
                              hipStream_t stream) {
    const float* x   = (const float*)d_in[0];
    const int*   ei  = (const int*)d_in[1];
    const float* W1  = (const float*)d_in[2];
    const float* as1 = (const float*)d_in[3];
    const float* ad1 = (const float*)d_in[4];
    const float* b1  = (const float*)d_in[5];
    const float* W2  = (const float*)d_in[6];
    const float* as2 = (const float*)d_in[7];
    const float* ad2 = (const float*)d_in[8];
    const float* b2  = (const float*)d_in[9];
    const float* Wl  = (const float*)d_in[10];
    const float* bl  = (const float*)d_in[11];
    float* out = (float*)d_out;

    const int* srcp = ei;
    const int* dstp = ei + NE;

    char* w = (char*)d_ws;
    int*   edge_src = (int*)w;  w += (size_t)ET*4;      //  6.8 MB
    f16*   hb       = (f16*)w;  w += (size_t)NN*64*2;   // 12.8 MB
    f16*   t1b      = (f16*)w;  w += (size_t)NN*64*2;   // 12.8 MB
    int*   rowst    = (int*)w;  w += (size_t)NN*4;
    int*   deg      = (int*)w;  w += (size_t)NN*4;
    float* ssrc     = (float*)w; w += (size_t)NN*4;
    float* sdst     = (float*)w; w += (size_t)NN*4;
    int*   bcnt     = (int*)w;  w += (size_t)NB*BST*4;
    int*   binbuf   = (int*)hb;     // aliases hb: dead before k_gemm<1> writes

    const int nbG = 782;                    // 3128 waves -> ~2 tiles each
    const int nbA = (NN/2 + 3)/4;           // 12500: 4 waves/block, 2 nodes/wave

    (void)hipMemsetAsync(bcnt, 0, (size_t)NB*BST*4, stream);
    k_bin  <<<NBIN, 256, 0, stream>>>(srcp, dstp, bcnt, binbuf);
    k_build<<<NB,   256, 0, stream>>>(bcnt, binbuf, edge_src, rowst, deg);

    // layer 1
    k_gemm<1><<<nbG, 256, 0, stream>>>((const void*)x, W1, as1, ad1, hb, ssrc, sdst);
    k_agg<1><<<nbA, 256, 0, stream>>>(rowst, deg, edge_src, ssrc, sdst, hb,
                                      b1, (const float*)nullptr, (const float*)nullptr,
                                      t1b, (float*)nullptr);
    // layer 2 + final linear
    k_gemm<0><<<nbG, 256, 0, stream>>>((const void*)t1b, W2, as2, ad2, hb, ssrc, sdst);
    k_agg<2><<<nbA, 256, 0, stream>>>(rowst, deg, edge_src, ssrc, sdst, hb,
                                      b2, Wl, bl,
                                      (f16*)nullptr, out);
}

// Round 7
// 224.254 us; speedup vs baseline: 1.7667x; 1.1075x over previous
//
#include <hip/hip_runtime.h>

#define NN 100000
#define NE 1600000
#define ET (NE + NN)
#define NB 391          // buckets of 256 dst nodes
#define CAP 5120        // slots/bucket (mean 4352, +12 sigma)
#define BST 16          // bcnt pad: 64B per counter
#define NBIN 256        // one block per CU
#define NCHK (ET/8)     // 212500 8-edge chunks; NE/8 = 200000 boundary
#define NTILE (NN/16)   // 6250 gemm tiles

typedef _Float16 f16;
typedef __attribute__((ext_vector_type(8))) _Float16 half8;
typedef __attribute__((ext_vector_type(4))) float f32x4;

__device__ __forceinline__ unsigned short hbits(float v){
    f16 h = (f16)v;
    return *(unsigned short*)&h;
}
// pack 2 f32 -> 2 f16 (round-to-zero) in one v_cvt_pk_rtz instruction
__device__ __forceinline__ unsigned pk16(float a, float b){
    auto p = __builtin_amdgcn_cvt_pkrtz(a, b);   // __fp16 ext_vector(2)
    return *(unsigned*)&p;
}
__device__ __forceinline__ float fast_tanh(float x){
    float e = __expf(2.f*x);
    return 1.f - __fdividef(2.f, e + 1.f);
}
// acc_lo += f16(lo half of h2) * a ; acc_hi += f16(hi half of h2) * a
__device__ __forceinline__ void fmix2(float& al, float& ah, unsigned h2, float a){
    asm("v_fma_mix_f32 %0, %2, %3, %0 op_sel_hi:[1,0,0]\n\t"
        "v_fma_mix_f32 %1, %2, %3, %1 op_sel:[1,0,0] op_sel_hi:[1,0,0]"
        : "+v"(al), "+v"(ah) : "v"(h2), "v"(a));
}

// ---------------- CSR build: bin by dst>>8, vectorized chunk loads ----------------
// Thread owns contiguous 8-edge chunks: one uint4x2 coalesced load per phase,
// THEN 8 LDS atomics -> memory latency paid ~3x/thread, not 100x.
__global__ void __launch_bounds__(256) k_bin(const int* __restrict__ src,
        const int* __restrict__ dst, int* __restrict__ bcnt,
        int* __restrict__ binbuf){
    __shared__ int cnt[NB];
    __shared__ int cur[NB];
    int t = threadIdx.x;
    for(int i=t;i<NB;i+=256) cnt[i]=0;
    __syncthreads();
    // phase 1: histogram (vector loads of dst)
    for(int g = blockIdx.x*256 + t; g < NCHK; g += NBIN*256){
        if(g < NE/8){
            const uint4* dp = (const uint4*)(dst + g*8);
            uint4 d0 = dp[0], d1 = dp[1];
            atomicAdd(&cnt[d0.x>>8],1); atomicAdd(&cnt[d0.y>>8],1);
            atomicAdd(&cnt[d0.z>>8],1); atomicAdd(&cnt[d0.w>>8],1);
            atomicAdd(&cnt[d1.x>>8],1); atomicAdd(&cnt[d1.y>>8],1);
            atomicAdd(&cnt[d1.z>>8],1); atomicAdd(&cnt[d1.w>>8],1);
        } else {
            int n0 = g*8 - NE;        // 8 consecutive self-loops
            #pragma unroll
            for(int i=0;i<8;i++) atomicAdd(&cnt[(n0+i)>>8],1);
        }
    }
    __syncthreads();
    // phase 2: one global reservation per bucket (chain depth = NBIN)
    for(int i=t;i<NB;i+=256){ int c=cnt[i]; cur[i] = c ? atomicAdd(&bcnt[i*BST], c) : 0; }
    __syncthreads();
    // phase 3: scatter into reserved runs (vector loads of src+dst)
    for(int g = blockIdx.x*256 + t; g < NCHK; g += NBIN*256){
        int s[8], d[8];
        if(g < NE/8){
            const uint4* sp = (const uint4*)(src + g*8);
            const uint4* dp = (const uint4*)(dst + g*8);
            uint4 s0 = sp[0], s1 = sp[1];
            uint4 d0 = dp[0], d1 = dp[1];
            s[0]=s0.x; s[1]=s0.y; s[2]=s0.z; s[3]=s0.w;
            s[4]=s1.x; s[5]=s1.y; s[6]=s1.z; s[7]=s1.w;
            d[0]=d0.x; d[1]=d0.y; d[2]=d0.z; d[3]=d0.w;
            d[4]=d1.x; d[5]=d1.y; d[6]=d1.z; d[7]=d1.w;
        } else {
            int n0 = g*8 - NE;
            #pragma unroll
            for(int i=0;i<8;i++){ s[i]=n0+i; d[i]=n0+i; }
        }
        #pragma unroll
        for(int i=0;i<8;i++){
            int b = d[i] >> 8;
            int pos = atomicAdd(&cur[b], 1);
            if(pos < CAP) binbuf[b*CAP + pos] = (s[i] << 8) | (d[i] & 255);
        }
    }
}

// ---------------- CSR build: per-bucket dense build (base prefix fused) ----------------
__global__ void __launch_bounds__(256) k_build(const int* __restrict__ bcnt,
        const int* __restrict__ binbuf, int* __restrict__ edge_src,
        int* __restrict__ rowst, int* __restrict__ deg){
    __shared__ int lsrc[CAP];
    __shared__ int ldeg[256], lscan[256], lcur[256], red[256];
    int b = blockIdx.x, t = threadIdx.x;
    int cnt = min(bcnt[b*BST], CAP);
    int part = 0;
    for(int i=t;i<b;i+=256) part += min(bcnt[i*BST], CAP);
    red[t] = part; __syncthreads();
    for(int off=128; off>=1; off>>=1){ if(t<off) red[t]+=red[t+off]; __syncthreads(); }
    int base = red[0];
    __syncthreads();
    ldeg[t] = 0; __syncthreads();
    const int* bb = binbuf + b*CAP;
    for(int i=t;i<cnt;i+=256) atomicAdd(&ldeg[bb[i] & 255], 1);
    __syncthreads();
    int dv = ldeg[t]; lscan[t] = dv; __syncthreads();
    for(int off=1; off<256; off<<=1){
        int u = (t>=off) ? lscan[t-off] : 0;
        __syncthreads(); lscan[t] += u; __syncthreads();
    }
    int excl = lscan[t] - dv; lcur[t] = excl;
    int node = b*256 + t;
    if(node < NN){ rowst[node] = base + excl; deg[node] = dv; }
    __syncthreads();
    for(int i=t;i<cnt;i+=256){
        int ent = bb[i];
        int pos = atomicAdd(&lcur[ent & 255], 1);
        lsrc[pos] = ent >> 8;
    }
    __syncthreads();
    for(int i=t;i<cnt;i+=256) edge_src[base+i] = lsrc[i];
}

// ---------------- h = x@W via f16 MFMA, s_src, s_dst ----------------
template<int FPIN>
__global__ void __launch_bounds__(256) k_gemm(const void* __restrict__ xin,
        const float* __restrict__ W, const float* __restrict__ avs,
        const float* __restrict__ avd, f16* __restrict__ hb,
        float* __restrict__ ssrc, float* __restrict__ sdst){
    int tid = threadIdx.x, lane = tid & 63;
    int col = lane & 15, q = lane >> 4;
    half8 Bf[2][4];
    #pragma unroll
    for(int kh=0;kh<2;kh++){
        #pragma unroll
        for(int nb=0;nb<4;nb++){
            half8 b;
            #pragma unroll
            for(int j=0;j<8;j++){
                float w = W[(kh*32 + q*8 + j)*64 + nb*16 + col];
                b[j] = (f16)w;
            }
            Bf[kh][nb] = b;
        }
    }
    float as[4], ad[4];
    #pragma unroll
    for(int nb=0;nb<4;nb++){ as[nb] = avs[nb*16+col]; ad[nb] = avd[nb*16+col]; }

    int gw = (blockIdx.x*256 + tid) >> 6;
    int nwaves = gridDim.x*4;
    for(int tile = gw; tile < NTILE; tile += nwaves){
        int n0 = tile*16;
        f32x4 acc[4];
        #pragma unroll
        for(int nb=0;nb<4;nb++) acc[nb] = (f32x4){0.f,0.f,0.f,0.f};
        #pragma unroll
        for(int kh=0;kh<2;kh++){
            half8 a;
            if(FPIN){
                const float4* xr = (const float4*)((const float*)xin
                                    + (size_t)(n0+col)*64 + kh*32 + q*8);
                float4 u = xr[0], v = xr[1];
                union { half8 h; uint4 u4; } A;
                A.u4.x = pk16(u.x, u.y);
                A.u4.y = pk16(u.z, u.w);
                A.u4.z = pk16(v.x, v.y);
                A.u4.w = pk16(v.z, v.w);
                a = A.h;
            } else {
                a = *(const half8*)((const f16*)xin
                                    + (size_t)(n0+col)*64 + kh*32 + q*8);
            }
            #pragma unroll
            for(int nb=0;nb<4;nb++)
                acc[nb] = __builtin_amdgcn_mfma_f32_16x16x32_f16(a, Bf[kh][nb], acc[nb], 0,0,0);
        }
        #pragma unroll
        for(int nb=0;nb<4;nb++){
            #pragma unroll
            for(int r=0;r<4;r++)
                hb[(size_t)(n0 + q*4 + r)*64 + nb*16 + col] = (f16)acc[nb][r];
        }
        #pragma unroll
        for(int r=0;r<4;r++){
            float ps = acc[0][r]*as[0] + acc[1][r]*as[1] + acc[2][r]*as[2] + acc[3][r]*as[3];
            float pd = acc[0][r]*ad[0] + acc[1][r]*ad[1] + acc[2][r]*ad[2] + acc[3][r]*ad[3];
            #pragma unroll
            for(int m=8;m>=1;m>>=1){ ps += __shfl_xor(ps,m); pd += __shfl_xor(pd,m); }
            if(col == 0){ ssrc[n0 + q*4 + r] = ps; sdst[n0 + q*4 + r] = pd; }
        }
    }
}

// ---------------- full-wave fallback: one node, any degree ----------------
template<int LAYER>
__device__ __forceinline__ void node_full(int node, int lane, int2* lp,
        const int* __restrict__ rowst, const int* __restrict__ deg,
        const int* __restrict__ edge_src, const float* __restrict__ ssrc,
        const float* __restrict__ sdst, const f16* __restrict__ hb,
        const float* __restrict__ bias, const float* __restrict__ Wl,
        const float* __restrict__ bl, f16* __restrict__ out1b,
        float* __restrict__ outF){
    int rs = rowst[node];
    int d  = deg[node];
    float sd = sdst[node];
    int g8 = lane >> 3;
    int c  = lane & 7;
    float a0=0.f,a1=0.f,a2=0.f,a3=0.f,a4=0.f,a5=0.f,a6=0.f,a7=0.f;

    float lmax = -1e30f;
    for(int j=lane; j<d; j+=64){
        int sj = edge_src[rs+j];
        float t = ssrc[sj] + sd;
        lmax = fmaxf(lmax, fmaxf(t, 0.2f*t));
    }
    #pragma unroll
    for(int m=32;m>=1;m>>=1) lmax = fmaxf(lmax, __shfl_xor(lmax,m));
    float lsum = 0.f;
    for(int j=lane; j<d; j+=64){
        int sj = edge_src[rs+j];
        float t = ssrc[sj] + sd;
        lsum += __expf(fmaxf(t, 0.2f*t) - lmax);
    }
    #pragma unroll
    for(int m=32;m>=1;m>>=1) lsum += __shfl_xor(lsum,m);
    float inv = 1.0f/(lsum + 1e-16f);
    for(int cb=0; cb<d; cb+=64){
        int s2 = 0; float al = 0.f;
        int j = cb + lane;
        if(j < d){
            s2 = edge_src[rs+j];
            float t = ssrc[s2] + sd;
            al = __expf(fmaxf(t, 0.2f*t) - lmax) * inv;
        }
        lp[lane] = make_int2(__float_as_int(al), s2);
        int dd = min(d - cb, 64);
        for(int i0=0; i0<dd; i0+=16){
            int2 e0 = lp[i0 + g8];
            int2 e1 = lp[i0 + 8 + g8];
            float f0 = __int_as_float(e0.x);
            float f1 = __int_as_float(e1.x);
            uint4 k0 = *(const uint4*)(hb + ((size_t)e0.y<<6) + (c<<3));
            uint4 k1 = *(const uint4*)(hb + ((size_t)e1.y<<6) + (c<<3));
            fmix2(a0,a1,k0.x,f0); fmix2(a2,a3,k0.y,f0);
            fmix2(a4,a5,k0.z,f0); fmix2(a6,a7,k0.w,f0);
            fmix2(a0,a1,k1.x,f1); fmix2(a2,a3,k1.y,f1);
            fmix2(a4,a5,k1.z,f1); fmix2(a6,a7,k1.w,f1);
        }
    }
    #pragma unroll
    for(int m=32;m>=8;m>>=1){
        a0 += __shfl_xor(a0,m); a1 += __shfl_xor(a1,m);
        a2 += __shfl_xor(a2,m); a3 += __shfl_xor(a3,m);
        a4 += __shfl_xor(a4,m); a5 += __shfl_xor(a5,m);
        a6 += __shfl_xor(a6,m); a7 += __shfl_xor(a7,m);
    }
    const float4* bp = (const float4*)bias;
    float4 bv0 = bp[c*2], bv1 = bp[c*2+1];
    if(LAYER == 1){
        if(g8 == 0){
            uint4 o;
            o.x = (unsigned)hbits(fast_tanh(a0+bv0.x)) | ((unsigned)hbits(fast_tanh(a1+bv0.y))<<16);
            o.y = (unsigned)hbits(fast_tanh(a2+bv0.z)) | ((unsigned)hbits(fast_tanh(a3+bv0.w))<<16);
            o.z = (unsigned)hbits(fast_tanh(a4+bv1.x)) | ((unsigned)hbits(fast_tanh(a5+bv1.y))<<16);
            o.w = (unsigned)hbits(fast_tanh(a6+bv1.z)) | ((unsigned)hbits(fast_tanh(a7+bv1.w))<<16);
            *(uint4*)(out1b + ((size_t)node<<6) + (c<<3)) = o;
        }
    } else {
        const float4* wp = (const float4*)Wl;
        float4 wv0 = wp[c*2], wv1 = wp[c*2+1];
        float r = (a0+bv0.x)*wv0.x + (a1+bv0.y)*wv0.y + (a2+bv0.z)*wv0.z + (a3+bv0.w)*wv0.w
                + (a4+bv1.x)*wv1.x + (a5+bv1.y)*wv1.y + (a6+bv1.z)*wv1.z + (a7+bv1.w)*wv1.w;
        r += __shfl_xor(r,1); r += __shfl_xor(r,2); r += __shfl_xor(r,4);
        if(lane == 0) outF[node] = r + bl[0];
    }
}

// ---------------- attention + aggregation: 2 nodes per wave ----------------
template<int LAYER>
__global__ void __launch_bounds__(256) k_agg(
        const int* __restrict__ rowst, const int* __restrict__ deg,
        const int* __restrict__ edge_src,
        const float* __restrict__ ssrc, const float* __restrict__ sdst,
        const f16* __restrict__ hb,
        const float* __restrict__ bias, const float* __restrict__ Wl,
        const float* __restrict__ bl,
        f16* __restrict__ out1b, float* __restrict__ outF){
    __shared__ int2 pairs[256];
    int tid = threadIdx.x;
    int wv   = (blockIdx.x*256 + tid) >> 6;   // wave id: 0..NN/2-1
    int lane = tid & 63;
    if(wv*2 >= NN) return;
    int2* lp = pairs + (tid & 192);           // wave-private 64-entry table
    int half = lane >> 5, l = lane & 31;
    int node = wv*2 + half;

    int rs = rowst[node];
    int d  = deg[node];
    float sd = sdst[node];
    int dmax = max(d, __shfl_xor(d, 32));

    if(dmax <= 32){
        // ---- per-half softmax ----
        int s = 0; float pr = 0.f;
        if(l < d){
            s = edge_src[rs + l];
            float t = ssrc[s] + sd;
            t = fmaxf(t, 0.2f*t);            // leaky_relu
            pr = __expf(fminf(t, 80.f));     // no max-shift: logits O(10)
        }
        float sm = pr;
        #pragma unroll
        for(int m=16;m>=1;m>>=1) sm += __shfl_xor(sm,m);
        float alpha = pr * (1.0f/(sm + 1e-16f));
        lp[lane] = make_int2(__float_as_int(alpha), s);   // lane = half*32+l

        // ---- gather: 8 edges/iter per half ----
        int g4 = l >> 3;                     // row-group 0..3
        int c  = l & 7;                      // channel chunk
        int base = half << 5;
        float a0=0.f,a1=0.f,a2=0.f,a3=0.f,a4=0.f,a5=0.f,a6=0.f,a7=0.f;
        for(int i0=0; i0<d; i0+=8){
            int2 e0 = lp[base + i0 + g4];
            int2 e1 = lp[base + i0 + 4 + g4];
            float f0 = __int_as_float(e0.x);
            float f1 = __int_as_float(e1.x);
            uint4 k0 = *(const uint4*)(hb + ((size_t)e0.y<<6) + (c<<3));
            uint4 k1 = *(const uint4*)(hb + ((size_t)e1.y<<6) + (c<<3));
            fmix2(a0,a1,k0.x,f0); fmix2(a2,a3,k0.y,f0);
            fmix2(a4,a5,k0.z,f0); fmix2(a6,a7,k0.w,f0);
            fmix2(a0,a1,k1.x,f1); fmix2(a2,a3,k1.y,f1);
            fmix2(a4,a5,k1.z,f1); fmix2(a6,a7,k1.w,f1);
        }

        // ---- channel-splitting fold over row-groups (lane bits 3,4) ----
        bool b3 = (l >> 3) & 1, b4 = (l >> 4) & 1;
        float u0 = b3 ? a4 : a0, v0 = b3 ? a0 : a4; u0 += __shfl_xor(v0, 8);
        float u1 = b3 ? a5 : a1, v1 = b3 ? a1 : a5; u1 += __shfl_xor(v1, 8);
        float u2 = b3 ? a6 : a2, v2 = b3 ? a2 : a6; u2 += __shfl_xor(v2, 8);
        float u3 = b3 ? a7 : a3, v3 = b3 ? a3 : a7; u3 += __shfl_xor(v3, 8);
        float w0 = b4 ? u2 : u0, z0 = b4 ? u0 : u2; w0 += __shfl_xor(z0, 16);
        float w1 = b4 ? u3 : u1, z1 = b4 ? u1 : u3; w1 += __shfl_xor(z1, 16);
        int ch0 = (c<<3) + ((int)b3<<2) + ((int)b4<<1);   // even; w1 = ch0+1

        if(LAYER == 1){
            float2 bv = ((const float2*)bias)[ch0>>1];
            unsigned o = pk16(fast_tanh(w0 + bv.x), fast_tanh(w1 + bv.y));
            *(unsigned*)(out1b + ((size_t)node<<6) + ch0) = o;
        } else {
            float2 bv = ((const float2*)bias)[ch0>>1];
            float2 wl = ((const float2*)Wl)[ch0>>1];
            float r = (w0 + bv.x)*wl.x + (w1 + bv.y)*wl.y;
            #pragma unroll
            for(int m=16;m>=1;m>>=1) r += __shfl_xor(r,m);
            if(l == 0) outF[node] = r + bl[0];
        }
    } else {
        // rare: a node with d>32 in this pair -> full-wave generic, twice
        node_full<LAYER>(wv*2,   lane, lp, rowst, deg, edge_src, ssrc, sdst,
                         hb, bias, Wl, bl, out1b, outF);
        node_full<LAYER>(wv*2+1, lane, lp, rowst, deg, edge_src, ssrc, sdst,
                         hb, bias, Wl, bl, out1b, outF);
    }
}

// ---------------- launch ----------------
extern "C" void kernel_launch(void* const* d_in, const int* in_sizes, int n_in,
                              void* d_out, int out_size, void* d_ws, size_t ws_size,
                              hipStream_t stream) {
    const float* x   = (const float*)d_in[0];
    const int*   ei  = (const int*)d_in[1];
    const float* W1  = (const float*)d_in[2];
    const float* as1 = (const float*)d_in[3];
    const float* ad1 = (const float*)d_in[4];
    const float* b1  = (const float*)d_in[5];
    const float* W2  = (const float*)d_in[6];
    const float* as2 = (const float*)d_in[7];
    const float* ad2 = (const float*)d_in[8];
    const float* b2  = (const float*)d_in[9];
    const float* Wl  = (const float*)d_in[10];
    const float* bl  = (const float*)d_in[11];
    float* out = (float*)d_out;

    const int* srcp = ei;
    const int* dstp = ei + NE;

    char* w = (char*)d_ws;
    int*   edge_src = (int*)w;  w += (size_t)ET*4;      //  6.8 MB
    f16*   hb       = (f16*)w;  w += (size_t)NN*64*2;   // 12.8 MB
    f16*   t1b      = (f16*)w;  w += (size_t)NN*64*2;   // 12.8 MB
    int*   rowst    = (int*)w;  w += (size_t)NN*4;
    int*   deg      = (int*)w;  w += (size_t)NN*4;
    float* ssrc     = (float*)w; w += (size_t)NN*4;
    float* sdst     = (float*)w; w += (size_t)NN*4;
    int*   bcnt     = (int*)w;  w += (size_t)NB*BST*4;
    int*   binbuf   = (int*)hb;     // aliases hb: dead before k_gemm<1> writes

    const int nbG = 782;                    // 3128 waves -> ~2 tiles each
    const int nbA = (NN/2 + 3)/4;           // 12500: 4 waves/block, 2 nodes/wave

    (void)hipMemsetAsync(bcnt, 0, (size_t)NB*BST*4, stream);
    k_bin  <<<NBIN, 256, 0, stream>>>(srcp, dstp, bcnt, binbuf);
    k_build<<<NB,   256, 0, stream>>>(bcnt, binbuf, edge_src, rowst, deg);

    // layer 1
    k_gemm<1><<<nbG, 256, 0, stream>>>((const void*)x, W1, as1, ad1, hb, ssrc, sdst);
    k_agg<1><<<nbA, 256, 0, stream>>>(rowst, deg, edge_src, ssrc, sdst, hb,
                                      b1, (const float*)nullptr, (const float*)nullptr,
                                      t1b, (float*)nullptr);
    // layer 2 + final linear
    k_gemm<0><<<nbG, 256, 0, stream>>>((const void*)t1b, W2, as2, ad2, hb, ssrc, sdst);
    k_agg<2><<<nbA, 256, 0, stream>>>(rowst, deg, edge_src, ssrc, sdst, hb,
                                      b2, Wl, bl,
                                      (f16*)nullptr, out);
}

// Round 8
// 216.316 us; speedup vs baseline: 1.8315x; 1.0367x over previous
//
#include <hip/hip_runtime.h>

#define NN 100000
#define NE 1600000
#define ET (NE + NN)
#define NB 391          // buckets of 256 dst nodes
#define CAP 5120        // slots/bucket (mean 4352, +12 sigma)
#define BST 16          // bcnt pad: 64B per counter
#define NBIN 256        // one block per CU
#define NCHK (ET/8)     // 212500 8-edge chunks; NE/8 = 200000 boundary
#define NTILE (NN/16)   // 6250 gemm tiles

typedef _Float16 f16;
typedef __attribute__((ext_vector_type(8))) _Float16 half8;
typedef __attribute__((ext_vector_type(4))) float f32x4;

__device__ __forceinline__ unsigned short hbits(float v){
    f16 h = (f16)v;
    return *(unsigned short*)&h;
}
// pack 2 f32 -> 2 f16 (round-to-zero) in one v_cvt_pk_rtz instruction
__device__ __forceinline__ unsigned pk16(float a, float b){
    auto p = __builtin_amdgcn_cvt_pkrtz(a, b);   // __fp16 ext_vector(2)
    return *(unsigned*)&p;
}
__device__ __forceinline__ float fast_tanh(float x){
    float e = __expf(2.f*x);
    return 1.f - __fdividef(2.f, e + 1.f);
}
// acc_lo += f16(lo half of h2) * a ; acc_hi += f16(hi half of h2) * a
__device__ __forceinline__ void fmix2(float& al, float& ah, unsigned h2, float a){
    asm("v_fma_mix_f32 %0, %2, %3, %0 op_sel_hi:[1,0,0]\n\t"
        "v_fma_mix_f32 %1, %2, %3, %1 op_sel:[1,0,0] op_sel_hi:[1,0,0]"
        : "+v"(al), "+v"(ah) : "v"(h2), "v"(a));
}

// ---------------- CSR build: bin by dst>>8, vectorized chunk loads ----------------
__global__ void __launch_bounds__(256) k_bin(const int* __restrict__ src,
        const int* __restrict__ dst, int* __restrict__ bcnt,
        int* __restrict__ binbuf){
    __shared__ int cnt[NB];
    __shared__ int cur[NB];
    int t = threadIdx.x;
    for(int i=t;i<NB;i+=256) cnt[i]=0;
    __syncthreads();
    // phase 1: histogram (vector loads of dst)
    for(int g = blockIdx.x*256 + t; g < NCHK; g += NBIN*256){
        if(g < NE/8){
            const uint4* dp = (const uint4*)(dst + g*8);
            uint4 d0 = dp[0], d1 = dp[1];
            atomicAdd(&cnt[d0.x>>8],1); atomicAdd(&cnt[d0.y>>8],1);
            atomicAdd(&cnt[d0.z>>8],1); atomicAdd(&cnt[d0.w>>8],1);
            atomicAdd(&cnt[d1.x>>8],1); atomicAdd(&cnt[d1.y>>8],1);
            atomicAdd(&cnt[d1.z>>8],1); atomicAdd(&cnt[d1.w>>8],1);
        } else {
            int n0 = g*8 - NE;        // 8 consecutive self-loops
            #pragma unroll
            for(int i=0;i<8;i++) atomicAdd(&cnt[(n0+i)>>8],1);
        }
    }
    __syncthreads();
    // phase 2: one global reservation per bucket (chain depth = NBIN)
    for(int i=t;i<NB;i+=256){ int c=cnt[i]; cur[i] = c ? atomicAdd(&bcnt[i*BST], c) : 0; }
    __syncthreads();
    // phase 3: scatter into reserved runs (vector loads of src+dst)
    for(int g = blockIdx.x*256 + t; g < NCHK; g += NBIN*256){
        int s[8], d[8];
        if(g < NE/8){
            const uint4* sp = (const uint4*)(src + g*8);
            const uint4* dp = (const uint4*)(dst + g*8);
            uint4 s0 = sp[0], s1 = sp[1];
            uint4 d0 = dp[0], d1 = dp[1];
            s[0]=s0.x; s[1]=s0.y; s[2]=s0.z; s[3]=s0.w;
            s[4]=s1.x; s[5]=s1.y; s[6]=s1.z; s[7]=s1.w;
            d[0]=d0.x; d[1]=d0.y; d[2]=d0.z; d[3]=d0.w;
            d[4]=d1.x; d[5]=d1.y; d[6]=d1.z; d[7]=d1.w;
        } else {
            int n0 = g*8 - NE;
            #pragma unroll
            for(int i=0;i<8;i++){ s[i]=n0+i; d[i]=n0+i; }
        }
        #pragma unroll
        for(int i=0;i<8;i++){
            int b = d[i] >> 8;
            int pos = atomicAdd(&cur[b], 1);
            if(pos < CAP) binbuf[b*CAP + pos] = (s[i] << 8) | (d[i] & 255);
        }
    }
}

// ---------------- CSR build: per-bucket dense build (base prefix fused) ----------------
__global__ void __launch_bounds__(256) k_build(const int* __restrict__ bcnt,
        const int* __restrict__ binbuf, int* __restrict__ edge_src,
        int* __restrict__ rowst, int* __restrict__ deg){
    __shared__ int lsrc[CAP];
    __shared__ int ldeg[256], lscan[256], lcur[256], red[256];
    int b = blockIdx.x, t = threadIdx.x;
    int cnt = min(bcnt[b*BST], CAP);
    int part = 0;
    for(int i=t;i<b;i+=256) part += min(bcnt[i*BST], CAP);
    red[t] = part; __syncthreads();
    for(int off=128; off>=1; off>>=1){ if(t<off) red[t]+=red[t+off]; __syncthreads(); }
    int base = red[0];
    __syncthreads();
    ldeg[t] = 0; __syncthreads();
    const int* bb = binbuf + b*CAP;
    for(int i=t;i<cnt;i+=256) atomicAdd(&ldeg[bb[i] & 255], 1);
    __syncthreads();
    int dv = ldeg[t]; lscan[t] = dv; __syncthreads();
    for(int off=1; off<256; off<<=1){
        int u = (t>=off) ? lscan[t-off] : 0;
        __syncthreads(); lscan[t] += u; __syncthreads();
    }
    int excl = lscan[t] - dv; lcur[t] = excl;
    int node = b*256 + t;
    if(node < NN){ rowst[node] = base + excl; deg[node] = dv; }
    __syncthreads();
    for(int i=t;i<cnt;i+=256){
        int ent = bb[i];
        int pos = atomicAdd(&lcur[ent & 255], 1);
        lsrc[pos] = ent >> 8;
    }
    __syncthreads();
    for(int i=t;i<cnt;i+=256) edge_src[base+i] = lsrc[i];
}

// ---------------- h = x@W via f16 MFMA, s_src, s_dst ----------------
template<int FPIN>
__global__ void __launch_bounds__(256) k_gemm(const void* __restrict__ xin,
        const float* __restrict__ W, const float* __restrict__ avs,
        const float* __restrict__ avd, f16* __restrict__ hb,
        float* __restrict__ ssrc, float* __restrict__ sdst){
    int tid = threadIdx.x, lane = tid & 63;
    int col = lane & 15, q = lane >> 4;
    half8 Bf[2][4];
    #pragma unroll
    for(int kh=0;kh<2;kh++){
        #pragma unroll
        for(int nb=0;nb<4;nb++){
            half8 b;
            #pragma unroll
            for(int j=0;j<8;j++){
                float w = W[(kh*32 + q*8 + j)*64 + nb*16 + col];
                b[j] = (f16)w;
            }
            Bf[kh][nb] = b;
        }
    }
    float as[4], ad[4];
    #pragma unroll
    for(int nb=0;nb<4;nb++){ as[nb] = avs[nb*16+col]; ad[nb] = avd[nb*16+col]; }

    int gw = (blockIdx.x*256 + tid) >> 6;
    int nwaves = gridDim.x*4;
    for(int tile = gw; tile < NTILE; tile += nwaves){
        int n0 = tile*16;
        f32x4 acc[4];
        #pragma unroll
        for(int nb=0;nb<4;nb++) acc[nb] = (f32x4){0.f,0.f,0.f,0.f};
        #pragma unroll
        for(int kh=0;kh<2;kh++){
            half8 a;
            if(FPIN){
                const float4* xr = (const float4*)((const float*)xin
                                    + (size_t)(n0+col)*64 + kh*32 + q*8);
                float4 u = xr[0], v = xr[1];
                union { half8 h; uint4 u4; } A;
                A.u4.x = pk16(u.x, u.y);
                A.u4.y = pk16(u.z, u.w);
                A.u4.z = pk16(v.x, v.y);
                A.u4.w = pk16(v.z, v.w);
                a = A.h;
            } else {
                a = *(const half8*)((const f16*)xin
                                    + (size_t)(n0+col)*64 + kh*32 + q*8);
            }
            #pragma unroll
            for(int nb=0;nb<4;nb++)
                acc[nb] = __builtin_amdgcn_mfma_f32_16x16x32_f16(a, Bf[kh][nb], acc[nb], 0,0,0);
        }
        #pragma unroll
        for(int nb=0;nb<4;nb++){
            #pragma unroll
            for(int r=0;r<4;r++)
                hb[(size_t)(n0 + q*4 + r)*64 + nb*16 + col] = (f16)acc[nb][r];
        }
        #pragma unroll
        for(int r=0;r<4;r++){
            float ps = acc[0][r]*as[0] + acc[1][r]*as[1] + acc[2][r]*as[2] + acc[3][r]*as[3];
            float pd = acc[0][r]*ad[0] + acc[1][r]*ad[1] + acc[2][r]*ad[2] + acc[3][r]*ad[3];
            #pragma unroll
            for(int m=8;m>=1;m>>=1){ ps += __shfl_xor(ps,m); pd += __shfl_xor(pd,m); }
            if(col == 0){ ssrc[n0 + q*4 + r] = ps; sdst[n0 + q*4 + r] = pd; }
        }
    }
}

// ---------------- full-wave fallback: one node, any degree ----------------
template<int LAYER>
__device__ __forceinline__ void node_full(int node, int lane, int2* lp,
        const int* __restrict__ rowst, const int* __restrict__ deg,
        const int* __restrict__ edge_src, const float* __restrict__ ssrc,
        const float* __restrict__ sdst, const f16* __restrict__ hb,
        const float* __restrict__ bias, const float* __restrict__ Wl,
        const float* __restrict__ bl, f16* __restrict__ out1b,
        float* __restrict__ outF){
    int rs = rowst[node];
    int d  = deg[node];
    float sd = sdst[node];
    int g8 = lane >> 3;
    int c  = lane & 7;
    float a0=0.f,a1=0.f,a2=0.f,a3=0.f,a4=0.f,a5=0.f,a6=0.f,a7=0.f;

    float lmax = -1e30f;
    for(int j=lane; j<d; j+=64){
        int sj = edge_src[rs+j];
        float t = ssrc[sj] + sd;
        lmax = fmaxf(lmax, fmaxf(t, 0.2f*t));
    }
    #pragma unroll
    for(int m=32;m>=1;m>>=1) lmax = fmaxf(lmax, __shfl_xor(lmax,m));
    float lsum = 0.f;
    for(int j=lane; j<d; j+=64){
        int sj = edge_src[rs+j];
        float t = ssrc[sj] + sd;
        lsum += __expf(fmaxf(t, 0.2f*t) - lmax);
    }
    #pragma unroll
    for(int m=32;m>=1;m>>=1) lsum += __shfl_xor(lsum,m);
    float inv = 1.0f/(lsum + 1e-16f);
    for(int cb=0; cb<d; cb+=64){
        int s2 = 0; float al = 0.f;
        int j = cb + lane;
        if(j < d){
            s2 = edge_src[rs+j];
            float t = ssrc[s2] + sd;
            al = __expf(fmaxf(t, 0.2f*t) - lmax) * inv;
        }
        lp[lane] = make_int2(__float_as_int(al), s2);
        int dd = min(d - cb, 64);
        for(int i0=0; i0<dd; i0+=16){
            int2 e0 = lp[i0 + g8];
            int2 e1 = lp[i0 + 8 + g8];
            float f0 = __int_as_float(e0.x);
            float f1 = __int_as_float(e1.x);
            uint4 k0 = *(const uint4*)(hb + ((size_t)e0.y<<6) + (c<<3));
            uint4 k1 = *(const uint4*)(hb + ((size_t)e1.y<<6) + (c<<3));
            fmix2(a0,a1,k0.x,f0); fmix2(a2,a3,k0.y,f0);
            fmix2(a4,a5,k0.z,f0); fmix2(a6,a7,k0.w,f0);
            fmix2(a0,a1,k1.x,f1); fmix2(a2,a3,k1.y,f1);
            fmix2(a4,a5,k1.z,f1); fmix2(a6,a7,k1.w,f1);
        }
    }
    #pragma unroll
    for(int m=32;m>=8;m>>=1){
        a0 += __shfl_xor(a0,m); a1 += __shfl_xor(a1,m);
        a2 += __shfl_xor(a2,m); a3 += __shfl_xor(a3,m);
        a4 += __shfl_xor(a4,m); a5 += __shfl_xor(a5,m);
        a6 += __shfl_xor(a6,m); a7 += __shfl_xor(a7,m);
    }
    const float4* bp = (const float4*)bias;
    float4 bv0 = bp[c*2], bv1 = bp[c*2+1];
    if(LAYER == 1){
        if(g8 == 0){
            uint4 o;
            o.x = (unsigned)hbits(fast_tanh(a0+bv0.x)) | ((unsigned)hbits(fast_tanh(a1+bv0.y))<<16);
            o.y = (unsigned)hbits(fast_tanh(a2+bv0.z)) | ((unsigned)hbits(fast_tanh(a3+bv0.w))<<16);
            o.z = (unsigned)hbits(fast_tanh(a4+bv1.x)) | ((unsigned)hbits(fast_tanh(a5+bv1.y))<<16);
            o.w = (unsigned)hbits(fast_tanh(a6+bv1.z)) | ((unsigned)hbits(fast_tanh(a7+bv1.w))<<16);
            *(uint4*)(out1b + ((size_t)node<<6) + (c<<3)) = o;
        }
    } else {
        const float4* wp = (const float4*)Wl;
        float4 wv0 = wp[c*2], wv1 = wp[c*2+1];
        float r = (a0+bv0.x)*wv0.x + (a1+bv0.y)*wv0.y + (a2+bv0.z)*wv0.z + (a3+bv0.w)*wv0.w
                + (a4+bv1.x)*wv1.x + (a5+bv1.y)*wv1.y + (a6+bv1.z)*wv1.z + (a7+bv1.w)*wv1.w;
        r += __shfl_xor(r,1); r += __shfl_xor(r,2); r += __shfl_xor(r,4);
        if(lane == 0) outF[node] = r + bl[0];
    }
}

// ---------------- attention + aggregation: 2 nodes per wave ----------------
// Fast path: all gather loads issued in one batch (static unroll, max 4
// iters for d<=32) -> one exposed memory latency per wave instead of d/8.

template<int LAYER>
__global__ void __launch_bounds__(256) k_agg(
        const int* __restrict__ rowst, const int* __restrict__ deg,
        const int* __restrict__ edge_src,
        const float* __restrict__ ssrc, const float* __restrict__ sdst,
        const f16* __restrict__ hb,
        const float* __restrict__ bias, const float* __restrict__ Wl,
        const float* __restrict__ bl,
        f16* __restrict__ out1b, float* __restrict__ outF){
    __shared__ int2 pairs[256];
    int tid = threadIdx.x;
    int wv   = (blockIdx.x*256 + tid) >> 6;   // wave id: 0..NN/2-1
    int lane = tid & 63;
    if(wv*2 >= NN) return;
    int2* lp = pairs + (tid & 192);           // wave-private 64-entry table
    int half = lane >> 5, l = lane & 31;
    int node = wv*2 + half;

    int rs = rowst[node];
    int d  = deg[node];
    float sd = sdst[node];
    int dmax = max(d, __shfl_xor(d, 32));

    if(dmax <= 32){
        // ---- per-half softmax ----
        int s = 0; float pr = 0.f;
        if(l < d){
            s = edge_src[rs + l];
            float t = ssrc[s] + sd;
            t = fmaxf(t, 0.2f*t);            // leaky_relu
            pr = __expf(fminf(t, 80.f));     // no max-shift: logits O(10)
        }
        float sm = pr;
        #pragma unroll
        for(int m=16;m>=1;m>>=1) sm += __shfl_xor(sm,m);
        float alpha = pr * (1.0f/(sm + 1e-16f));
        lp[lane] = make_int2(__float_as_int(alpha), s);   // lane = half*32+l

        // ---- gather: batch-issue ALL loads, then all FMAs ----
        int g4 = l >> 3;                     // row-group 0..3
        int c  = l & 7;                      // channel chunk
        int base = half << 5;
        int nitw = (dmax + 7) >> 3;          // 1..4, wave-uniform
        float F0[4], F1[4];
        uint4 K0[4], K1[4];
        #pragma unroll
        for(int it=0; it<4; it++){
            if(it < nitw){
                int2 e0 = lp[base + it*8 + g4];
                int2 e1 = lp[base + it*8 + 4 + g4];
                F0[it] = __int_as_float(e0.x);
                F1[it] = __int_as_float(e1.x);
                K0[it] = *(const uint4*)(hb + ((size_t)e0.y<<6) + (c<<3));
                K1[it] = *(const uint4*)(hb + ((size_t)e1.y<<6) + (c<<3));
            }
        }
        float a0=0.f,a1=0.f,a2=0.f,a3=0.f,a4=0.f,a5=0.f,a6=0.f,a7=0.f;
        #pragma unroll
        for(int it=0; it<4; it++){
            if(it < nitw){
                fmix2(a0,a1,K0[it].x,F0[it]); fmix2(a2,a3,K0[it].y,F0[it]);
                fmix2(a4,a5,K0[it].z,F0[it]); fmix2(a6,a7,K0[it].w,F0[it]);
                fmix2(a0,a1,K1[it].x,F1[it]); fmix2(a2,a3,K1[it].y,F1[it]);
                fmix2(a4,a5,K1[it].z,F1[it]); fmix2(a6,a7,K1[it].w,F1[it]);
            }
        }

        // ---- channel-splitting fold over row-groups (lane bits 3,4) ----
        bool b3 = (l >> 3) & 1, b4 = (l >> 4) & 1;
        float u0 = b3 ? a4 : a0, v0 = b3 ? a0 : a4; u0 += __shfl_xor(v0, 8);
        float u1 = b3 ? a5 : a1, v1 = b3 ? a1 : a5; u1 += __shfl_xor(v1, 8);
        float u2 = b3 ? a6 : a2, v2 = b3 ? a2 : a6; u2 += __shfl_xor(v2, 8);
        float u3 = b3 ? a7 : a3, v3 = b3 ? a3 : a7; u3 += __shfl_xor(v3, 8);
        float w0 = b4 ? u2 : u0, z0 = b4 ? u0 : u2; w0 += __shfl_xor(z0, 16);
        float w1 = b4 ? u3 : u1, z1 = b4 ? u1 : u3; w1 += __shfl_xor(z1, 16);
        int ch0 = (c<<3) + ((int)b3<<2) + ((int)b4<<1);   // even; w1 = ch0+1

        if(LAYER == 1){
            float2 bv = ((const float2*)bias)[ch0>>1];
            unsigned o = pk16(fast_tanh(w0 + bv.x), fast_tanh(w1 + bv.y));
            *(unsigned*)(out1b + ((size_t)node<<6) + ch0) = o;
        } else {
            float2 bv = ((const float2*)bias)[ch0>>1];
            float2 wl = ((const float2*)Wl)[ch0>>1];
            float r = (w0 + bv.x)*wl.x + (w1 + bv.y)*wl.y;
            #pragma unroll
            for(int m=16;m>=1;m>>=1) r += __shfl_xor(r,m);
            if(l == 0) outF[node] = r + bl[0];
        }
    } else {
        // rare: a node with d>32 in this pair -> full-wave generic, twice
        node_full<LAYER>(wv*2,   lane, lp, rowst, deg, edge_src, ssrc, sdst,
                         hb, bias, Wl, bl, out1b, outF);
        node_full<LAYER>(wv*2+1, lane, lp, rowst, deg, edge_src, ssrc, sdst,
                         hb, bias, Wl, bl, out1b, outF);
    }
}

// ---------------- launch ----------------
extern "C" void kernel_launch(void* const* d_in, const int* in_sizes, int n_in,
                              void* d_out, int out_size, void* d_ws, size_t ws_size,
                              hipStream_t stream) {
    const float* x   = (const float*)d_in[0];
    const int*   ei  = (const int*)d_in[1];
    const float* W1  = (const float*)d_in[2];
    const float* as1 = (const float*)d_in[3];
    const float* ad1 = (const float*)d_in[4];
    const float* b1  = (const float*)d_in[5];
    const float* W2  = (const float*)d_in[6];
    const float* as2 = (const float*)d_in[7];
    const float* ad2 = (const float*)d_in[8];
    const float* b2  = (const float*)d_in[9];
    const float* Wl  = (const float*)d_in[10];
    const float* bl  = (const float*)d_in[11];
    float* out = (float*)d_out;

    const int* srcp = ei;
    const int* dstp = ei + NE;

    char* w = (char*)d_ws;
    int*   edge_src = (int*)w;  w += (size_t)ET*4;      //  6.8 MB
    f16*   hb       = (f16*)w;  w += (size_t)NN*64*2;   // 12.8 MB
    f16*   t1b      = (f16*)w;  w += (size_t)NN*64*2;   // 12.8 MB
    int*   rowst    = (int*)w;  w += (size_t)NN*4;
    int*   deg      = (int*)w;  w += (size_t)NN*4;
    float* ssrc     = (float*)w; w += (size_t)NN*4;
    float* sdst     = (float*)w; w += (size_t)NN*4;
    int*   bcnt     = (int*)w;  w += (size_t)NB*BST*4;
    int*   binbuf   = (int*)hb;     // aliases hb: dead before k_gemm<1> writes

    const int nbG = 782;                    // 3128 waves -> ~2 tiles each
    const int nbA = (NN/2 + 3)/4;           // 12500: 4 waves/block, 2 nodes/wave

    (void)hipMemsetAsync(bcnt, 0, (size_t)NB*BST*4, stream);
    k_bin  <<<NBIN, 256, 0, stream>>>(srcp, dstp, bcnt, binbuf);
    k_build<<<NB,   256, 0, stream>>>(bcnt, binbuf, edge_src, rowst, deg);

    // layer 1
    k_gemm<1><<<nbG, 256, 0, stream>>>((const void*)x, W1, as1, ad1, hb, ssrc, sdst);
    k_agg<1><<<nbA, 256, 0, stream>>>(rowst, deg, edge_src, ssrc, sdst, hb,
                                      b1, (const float*)nullptr, (const float*)nullptr,
                                      t1b, (float*)nullptr);
    // layer 2 + final linear
    k_gemm<0><<<nbG, 256, 0, stream>>>((const void*)t1b, W2, as2, ad2, hb, ssrc, sdst);
    k_agg<2><<<nbA, 256, 0, stream>>>(rowst, deg, edge_src, ssrc, sdst, hb,
                                      b2, Wl, bl,
                                      (f16*)nullptr, out);
}

// Round 11
// 197.392 us; speedup vs baseline: 2.0071x; 1.0959x over previous
//
#include <hip/hip_runtime.h>

#define NN 100000
#define NE 1600000
#define ET (NE + NN)
#define NB 391          // buckets of 256 dst nodes
#define CAP 5120        // slots/bucket (mean 4352, +12 sigma)
#define BST 16          // bcnt pad: 64B per counter
#define NBIN 256        // one block per CU
#define NCHK (ET/8)     // 212500 8-edge chunks; NE/8 = 200000 boundary
#define NTILE (NN/16)   // 6250 gemm tiles

typedef _Float16 f16;
typedef __attribute__((ext_vector_type(8))) _Float16 half8;
typedef __attribute__((ext_vector_type(4))) float f32x4;

__device__ __forceinline__ unsigned short hbits(float v){
    f16 h = (f16)v;
    return *(unsigned short*)&h;
}
// pack 2 f32 -> 2 f16 (round-to-zero) in one v_cvt_pk_rtz instruction
__device__ __forceinline__ unsigned pk16(float a, float b){
    auto p = __builtin_amdgcn_cvt_pkrtz(a, b);   // __fp16 ext_vector(2)
    return *(unsigned*)&p;
}
__device__ __forceinline__ float fast_tanh(float x){
    float e = __expf(2.f*x);
    return 1.f - __fdividef(2.f, e + 1.f);
}
// acc_lo += f16(lo half of h2) * a ; acc_hi += f16(hi half of h2) * a
__device__ __forceinline__ void fmix2(float& al, float& ah, unsigned h2, float a){
    asm("v_fma_mix_f32 %0, %2, %3, %0 op_sel_hi:[1,0,0]\n\t"
        "v_fma_mix_f32 %1, %2, %3, %1 op_sel:[1,0,0] op_sel_hi:[1,0,0]"
        : "+v"(al), "+v"(ah) : "v"(h2), "v"(a));
}

// ---------------- CSR build: bin by dst>>8, vectorized chunk loads ----------------
__global__ void __launch_bounds__(256) k_bin(const int* __restrict__ src,
        const int* __restrict__ dst, int* __restrict__ bcnt,
        int* __restrict__ binbuf){
    __shared__ int cnt[NB];
    __shared__ int cur[NB];
    int t = threadIdx.x;
    for(int i=t;i<NB;i+=256) cnt[i]=0;
    __syncthreads();
    // phase 1: histogram (vector loads of dst)
    for(int g = blockIdx.x*256 + t; g < NCHK; g += NBIN*256){
        if(g < NE/8){
            const uint4* dp = (const uint4*)(dst + g*8);
            uint4 d0 = dp[0], d1 = dp[1];
            atomicAdd(&cnt[d0.x>>8],1); atomicAdd(&cnt[d0.y>>8],1);
            atomicAdd(&cnt[d0.z>>8],1); atomicAdd(&cnt[d0.w>>8],1);
            atomicAdd(&cnt[d1.x>>8],1); atomicAdd(&cnt[d1.y>>8],1);
            atomicAdd(&cnt[d1.z>>8],1); atomicAdd(&cnt[d1.w>>8],1);
        } else {
            int n0 = g*8 - NE;        // 8 consecutive self-loops
            #pragma unroll
            for(int i=0;i<8;i++) atomicAdd(&cnt[(n0+i)>>8],1);
        }
    }
    __syncthreads();
    // phase 2: one global reservation per bucket (chain depth = NBIN)
    for(int i=t;i<NB;i+=256){ int c=cnt[i]; cur[i] = c ? atomicAdd(&bcnt[i*BST], c) : 0; }
    __syncthreads();
    // phase 3: scatter into reserved runs (vector loads of src+dst)
    for(int g = blockIdx.x*256 + t; g < NCHK; g += NBIN*256){
        int s[8], d[8];
        if(g < NE/8){
            const uint4* sp = (const uint4*)(src + g*8);
            const uint4* dp = (const uint4*)(dst + g*8);
            uint4 s0 = sp[0], s1 = sp[1];
            uint4 d0 = dp[0], d1 = dp[1];
            s[0]=s0.x; s[1]=s0.y; s[2]=s0.z; s[3]=s0.w;
            s[4]=s1.x; s[5]=s1.y; s[6]=s1.z; s[7]=s1.w;
            d[0]=d0.x; d[1]=d0.y; d[2]=d0.z; d[3]=d0.w;
            d[4]=d1.x; d[5]=d1.y; d[6]=d1.z; d[7]=d1.w;
        } else {
            int n0 = g*8 - NE;
            #pragma unroll
            for(int i=0;i<8;i++){ s[i]=n0+i; d[i]=n0+i; }
        }
        #pragma unroll
        for(int i=0;i<8;i++){
            int b = d[i] >> 8;
            int pos = atomicAdd(&cur[b], 1);
            if(pos < CAP) binbuf[b*CAP + pos] = (s[i] << 8) | (d[i] & 255);
        }
    }
}

// ---------------- CSR build: per-bucket dense build (base prefix fused) ----------------
__global__ void __launch_bounds__(256) k_build(const int* __restrict__ bcnt,
        const int* __restrict__ binbuf, int* __restrict__ edge_src,
        int* __restrict__ rowst, int* __restrict__ deg){
    __shared__ int lsrc[CAP];
    __shared__ int ldeg[256], lscan[256], lcur[256], red[256];
    int b = blockIdx.x, t = threadIdx.x;
    int cnt = min(bcnt[b*BST], CAP);
    int part = 0;
    for(int i=t;i<b;i+=256) part += min(bcnt[i*BST], CAP);
    red[t] = part; __syncthreads();
    for(int off=128; off>=1; off>>=1){ if(t<off) red[t]+=red[t+off]; __syncthreads(); }
    int base = red[0];
    __syncthreads();
    ldeg[t] = 0; __syncthreads();
    const int* bb = binbuf + b*CAP;
    for(int i=t;i<cnt;i+=256) atomicAdd(&ldeg[bb[i] & 255], 1);
    __syncthreads();
    int dv = ldeg[t]; lscan[t] = dv; __syncthreads();
    for(int off=1; off<256; off<<=1){
        int u = (t>=off) ? lscan[t-off] : 0;
        __syncthreads(); lscan[t] += u; __syncthreads();
    }
    int excl = lscan[t] - dv; lcur[t] = excl;
    int node = b*256 + t;
    if(node < NN){ rowst[node] = base + excl; deg[node] = dv; }
    __syncthreads();
    for(int i=t;i<cnt;i+=256){
        int ent = bb[i];
        int pos = atomicAdd(&lcur[ent & 255], 1);
        lsrc[pos] = ent >> 8;
    }
    __syncthreads();
    for(int i=t;i<cnt;i+=256) edge_src[base+i] = lsrc[i];
}

// ---------------- h = x@W via f16 MFMA, s_src, s_dst (+g for layer 2) ----------------
// L2=1: also compute g[n] = h[n].Wl (scalar, T_OUT=1) and SKIP the h store
// (layer-2 aggregation only needs scalars: out = (sum pr*g)/(sum pr) + const).
template<int FPIN, int L2>
__global__ void __launch_bounds__(256) k_gemm(const void* __restrict__ xin,
        const float* __restrict__ W, const float* __restrict__ avs,
        const float* __restrict__ avd, const float* __restrict__ Wlv,
        f16* __restrict__ hb, float* __restrict__ ssrc,
        float* __restrict__ sdst, float* __restrict__ gsc){
    int tid = threadIdx.x, lane = tid & 63;
    int col = lane & 15, q = lane >> 4;
    half8 Bf[2][4];
    #pragma unroll
    for(int kh=0;kh<2;kh++){
        #pragma unroll
        for(int nb=0;nb<4;nb++){
            half8 b;
            #pragma unroll
            for(int j=0;j<8;j++){
                float w = W[(kh*32 + q*8 + j)*64 + nb*16 + col];
                b[j] = (f16)w;
            }
            Bf[kh][nb] = b;
        }
    }
    float as[4], ad[4], wl[4];
    #pragma unroll
    for(int nb=0;nb<4;nb++){
        as[nb] = avs[nb*16+col]; ad[nb] = avd[nb*16+col];
        wl[nb] = L2 ? Wlv[nb*16+col] : 0.f;
    }

    int gw = (blockIdx.x*256 + tid) >> 6;
    int nwaves = gridDim.x*4;
    for(int tile = gw; tile < NTILE; tile += nwaves){
        int n0 = tile*16;
        f32x4 acc[4];
        #pragma unroll
        for(int nb=0;nb<4;nb++) acc[nb] = (f32x4){0.f,0.f,0.f,0.f};
        #pragma unroll
        for(int kh=0;kh<2;kh++){
            half8 a;
            if(FPIN){
                const float4* xr = (const float4*)((const float*)xin
                                    + (size_t)(n0+col)*64 + kh*32 + q*8);
                float4 u = xr[0], v = xr[1];
                union { half8 h; uint4 u4; } A;
                A.u4.x = pk16(u.x, u.y);
                A.u4.y = pk16(u.z, u.w);
                A.u4.z = pk16(v.x, v.y);
                A.u4.w = pk16(v.z, v.w);
                a = A.h;
            } else {
                a = *(const half8*)((const f16*)xin
                                    + (size_t)(n0+col)*64 + kh*32 + q*8);
            }
            #pragma unroll
            for(int nb=0;nb<4;nb++)
                acc[nb] = __builtin_amdgcn_mfma_f32_16x16x32_f16(a, Bf[kh][nb], acc[nb], 0,0,0);
        }
        if(!L2){
            #pragma unroll
            for(int nb=0;nb<4;nb++){
                #pragma unroll
                for(int r=0;r<4;r++)
                    hb[(size_t)(n0 + q*4 + r)*64 + nb*16 + col] = (f16)acc[nb][r];
            }
        }
        #pragma unroll
        for(int r=0;r<4;r++){
            float ps = acc[0][r]*as[0] + acc[1][r]*as[1] + acc[2][r]*as[2] + acc[3][r]*as[3];
            float pd = acc[0][r]*ad[0] + acc[1][r]*ad[1] + acc[2][r]*ad[2] + acc[3][r]*ad[3];
            float pg = L2 ? (acc[0][r]*wl[0] + acc[1][r]*wl[1] + acc[2][r]*wl[2] + acc[3][r]*wl[3]) : 0.f;
            #pragma unroll
            for(int m=8;m>=1;m>>=1){
                ps += __shfl_xor(ps,m); pd += __shfl_xor(pd,m);
                if(L2) pg += __shfl_xor(pg,m);
            }
            if(col == 0){
                ssrc[n0 + q*4 + r] = ps; sdst[n0 + q*4 + r] = pd;
                if(L2) gsc[n0 + q*4 + r] = pg;
            }
        }
    }
}

// ---------------- full-wave fallback (layer 1): one node, any degree ----------------
__device__ __forceinline__ void node_full1(int node, int lane, int2* lp,
        const int* __restrict__ rowst, const int* __restrict__ deg,
        const int* __restrict__ edge_src, const float* __restrict__ ssrc,
        const float* __restrict__ sdst, const f16* __restrict__ hb,
        const float* __restrict__ bias, f16* __restrict__ out1b){
    int rs = rowst[node];
    int d  = deg[node];
    float sd = sdst[node];
    int g8 = lane >> 3;
    int c  = lane & 7;
    float a0=0.f,a1=0.f,a2=0.f,a3=0.f,a4=0.f,a5=0.f,a6=0.f,a7=0.f;

    float lmax = -1e30f;
    for(int j=lane; j<d; j+=64){
        int sj = edge_src[rs+j];
        float t = ssrc[sj] + sd;
        lmax = fmaxf(lmax, fmaxf(t, 0.2f*t));
    }
    #pragma unroll
    for(int m=32;m>=1;m>>=1) lmax = fmaxf(lmax, __shfl_xor(lmax,m));
    float lsum = 0.f;
    for(int j=lane; j<d; j+=64){
        int sj = edge_src[rs+j];
        float t = ssrc[sj] + sd;
        lsum += __expf(fmaxf(t, 0.2f*t) - lmax);
    }
    #pragma unroll
    for(int m=32;m>=1;m>>=1) lsum += __shfl_xor(lsum,m);
    float inv = 1.0f/(lsum + 1e-16f);
    for(int cb=0; cb<d; cb+=64){
        int s2 = 0; float al = 0.f;
        int j = cb + lane;
        if(j < d){
            s2 = edge_src[rs+j];
            float t = ssrc[s2] + sd;
            al = __expf(fmaxf(t, 0.2f*t) - lmax) * inv;
        }
        lp[lane] = make_int2(__float_as_int(al), s2);
        int dd = min(d - cb, 64);
        for(int i0=0; i0<dd; i0+=16){
            int2 e0 = lp[i0 + g8];
            int2 e1 = lp[i0 + 8 + g8];
            float f0 = __int_as_float(e0.x);
            float f1 = __int_as_float(e1.x);
            uint4 k0 = *(const uint4*)(hb + ((size_t)e0.y<<6) + (c<<3));
            uint4 k1 = *(const uint4*)(hb + ((size_t)e1.y<<6) + (c<<3));
            fmix2(a0,a1,k0.x,f0); fmix2(a2,a3,k0.y,f0);
            fmix2(a4,a5,k0.z,f0); fmix2(a6,a7,k0.w,f0);
            fmix2(a0,a1,k1.x,f1); fmix2(a2,a3,k1.y,f1);
            fmix2(a4,a5,k1.z,f1); fmix2(a6,a7,k1.w,f1);
        }
    }
    #pragma unroll
    for(int m=32;m>=8;m>>=1){
        a0 += __shfl_xor(a0,m); a1 += __shfl_xor(a1,m);
        a2 += __shfl_xor(a2,m); a3 += __shfl_xor(a3,m);
        a4 += __shfl_xor(a4,m); a5 += __shfl_xor(a5,m);
        a6 += __shfl_xor(a6,m); a7 += __shfl_xor(a7,m);
    }
    const float4* bp = (const float4*)bias;
    float4 bv0 = bp[c*2], bv1 = bp[c*2+1];
    if(g8 == 0){
        uint4 o;
        o.x = (unsigned)hbits(fast_tanh(a0+bv0.x)) | ((unsigned)hbits(fast_tanh(a1+bv0.y))<<16);
        o.y = (unsigned)hbits(fast_tanh(a2+bv0.z)) | ((unsigned)hbits(fast_tanh(a3+bv0.w))<<16);
        o.z = (unsigned)hbits(fast_tanh(a4+bv1.x)) | ((unsigned)hbits(fast_tanh(a5+bv1.y))<<16);
        o.w = (unsigned)hbits(fast_tanh(a6+bv1.z)) | ((unsigned)hbits(fast_tanh(a7+bv1.w))<<16);
        *(uint4*)(out1b + ((size_t)node<<6) + (c<<3)) = o;
    }
}

// ---------------- layer-1 aggregation: 2 nodes per wave ----------------
__global__ void __launch_bounds__(256) k_agg1(
        const int* __restrict__ rowst, const int* __restrict__ deg,
        const int* __restrict__ edge_src,
        const float* __restrict__ ssrc, const float* __restrict__ sdst,
        const f16* __restrict__ hb, const float* __restrict__ bias,
        f16* __restrict__ out1b){
    __shared__ int2 pairs[256];
    int tid = threadIdx.x;
    int wv   = (blockIdx.x*256 + tid) >> 6;   // wave id: 0..NN/2-1
    int lane = tid & 63;
    if(wv*2 >= NN) return;
    int2* lp = pairs + (tid & 192);           // wave-private 64-entry table
    int half = lane >> 5, l = lane & 31;
    int node = wv*2 + half;

    int rs = rowst[node];
    int d  = deg[node];
    float sd = sdst[node];
    int dmax = max(d, __shfl_xor(d, 32));

    if(dmax <= 32){
        // ---- per-half softmax ----
        int s = 0; float pr = 0.f;
        if(l < d){
            s = edge_src[rs + l];
            float t = ssrc[s] + sd;
            t = fmaxf(t, 0.2f*t);            // leaky_relu
            pr = __expf(fminf(t, 80.f));     // no max-shift: logits O(10)
        }
        float sm = pr;
        #pragma unroll
        for(int m=16;m>=1;m>>=1) sm += __shfl_xor(sm,m);
        float alpha = pr * (1.0f/(sm + 1e-16f));
        lp[lane] = make_int2(__float_as_int(alpha), s);   // lane = half*32+l

        // ---- gather: batch-issue ALL loads, then all FMAs ----
        int g4 = l >> 3;                     // row-group 0..3
        int c  = l & 7;                      // channel chunk
        int base = half << 5;
        int nitw = (dmax + 7) >> 3;          // 1..4, wave-uniform
        float F0[4], F1[4];
        uint4 K0[4], K1[4];
        #pragma unroll
        for(int it=0; it<4; it++){
            if(it < nitw){
                int2 e0 = lp[base + it*8 + g4];
                int2 e1 = lp[base + it*8 + 4 + g4];
                F0[it] = __int_as_float(e0.x);
                F1[it] = __int_as_float(e1.x);
                K0[it] = *(const uint4*)(hb + ((size_t)e0.y<<6) + (c<<3));
                K1[it] = *(const uint4*)(hb + ((size_t)e1.y<<6) + (c<<3));
            }
        }
        float a0=0.f,a1=0.f,a2=0.f,a3=0.f,a4=0.f,a5=0.f,a6=0.f,a7=0.f;
        #pragma unroll
        for(int it=0; it<4; it++){
            if(it < nitw){
                fmix2(a0,a1,K0[it].x,F0[it]); fmix2(a2,a3,K0[it].y,F0[it]);
                fmix2(a4,a5,K0[it].z,F0[it]); fmix2(a6,a7,K0[it].w,F0[it]);
                fmix2(a0,a1,K1[it].x,F1[it]); fmix2(a2,a3,K1[it].y,F1[it]);
                fmix2(a4,a5,K1[it].z,F1[it]); fmix2(a6,a7,K1[it].w,F1[it]);
            }
        }

        // ---- channel-splitting fold over row-groups (lane bits 3,4) ----
        bool b3 = (l >> 3) & 1, b4 = (l >> 4) & 1;
        float u0 = b3 ? a4 : a0, v0 = b3 ? a0 : a4; u0 += __shfl_xor(v0, 8);
        float u1 = b3 ? a5 : a1, v1 = b3 ? a1 : a5; u1 += __shfl_xor(v1, 8);
        float u2 = b3 ? a6 : a2, v2 = b3 ? a2 : a6; u2 += __shfl_xor(v2, 8);
        float u3 = b3 ? a7 : a3, v3 = b3 ? a3 : a7; u3 += __shfl_xor(v3, 8);
        float w0 = b4 ? u2 : u0, z0 = b4 ? u0 : u2; w0 += __shfl_xor(z0, 16);
        float w1 = b4 ? u3 : u1, z1 = b4 ? u1 : u3; w1 += __shfl_xor(z1, 16);
        int ch0 = (c<<3) + ((int)b3<<2) + ((int)b4<<1);   // even; w1 = ch0+1

        float2 bv = ((const float2*)bias)[ch0>>1];
        unsigned o = pk16(fast_tanh(w0 + bv.x), fast_tanh(w1 + bv.y));
        *(unsigned*)(out1b + ((size_t)node<<6) + ch0) = o;
    } else {
        // rare: a node with d>32 in this pair -> full-wave generic, twice
        node_full1(wv*2,   lane, lp, rowst, deg, edge_src, ssrc, sdst, hb, bias, out1b);
        node_full1(wv*2+1, lane, lp, rowst, deg, edge_src, ssrc, sdst, hb, bias, out1b);
    }
}

// ---------------- layer-2 aggregation: scalar (uses g = h.Wl) ----------------
// out[n] = (sum_j pr_j * g[s_j]) / (sum_j pr_j) + (b2.Wl + bl)
__global__ void __launch_bounds__(256) k_agg2(
        const int* __restrict__ rowst, const int* __restrict__ deg,
        const int* __restrict__ edge_src,
        const float* __restrict__ ssrc, const float* __restrict__ sdst,
        const float* __restrict__ gsc, const float* __restrict__ bias,
        const float* __restrict__ Wl, const float* __restrict__ bl,
        float* __restrict__ outF){
    int tid = threadIdx.x;
    int wv   = (blockIdx.x*256 + tid) >> 6;
    int lane = tid & 63;
    if(wv*2 >= NN) return;
    int half = lane >> 5, l = lane & 31;
    int node = wv*2 + half;

    // c2 = b2.Wl, computed cooperatively: lane l covers channels 2l, 2l+1.
    // xor-reduce masks 16..1 within each 32-lane half -> every lane holds c2.
    float2 bv = ((const float2*)bias)[l];
    float2 wl = ((const float2*)Wl)[l];
    float rc = bv.x*wl.x + bv.y*wl.y;
    #pragma unroll
    for(int m=16;m>=1;m>>=1) rc += __shfl_xor(rc,m);

    int rs = rowst[node];
    int d  = deg[node];
    float sd = sdst[node];
    int dmax = max(d, __shfl_xor(d, 32));

    if(dmax <= 32){
        float pr = 0.f, gv = 0.f;
        if(l < d){
            int s = edge_src[rs + l];
            float t = ssrc[s] + sd;
            t = fmaxf(t, 0.2f*t);
            pr = __expf(fminf(t, 80.f));
            gv = gsc[s];
        }
        float sm = pr, num = pr*gv;
        #pragma unroll
        for(int m=16;m>=1;m>>=1){ sm += __shfl_xor(sm,m); num += __shfl_xor(num,m); }
        if(l == 0) outF[node] = num/(sm + 1e-16f) + rc + bl[0];
    } else {
        // rare: full-wave generic with max-shift, both nodes sequentially
        #pragma unroll 1
        for(int k=0;k<2;k++){
            int nd = wv*2 + k;
            int rs2 = rowst[nd], d2 = deg[nd];
            float sd2 = sdst[nd];
            float lmax = -1e30f;
            for(int j=lane; j<d2; j+=64){
                int sj = edge_src[rs2+j];
                float t = ssrc[sj] + sd2;
                lmax = fmaxf(lmax, fmaxf(t, 0.2f*t));
            }
            #pragma unroll
            for(int m=32;m>=1;m>>=1) lmax = fmaxf(lmax, __shfl_xor(lmax,m));
            float lsum = 0.f, lnum = 0.f;
            for(int j=lane; j<d2; j+=64){
                int sj = edge_src[rs2+j];
                float t = ssrc[sj] + sd2;
                float e = __expf(fmaxf(t, 0.2f*t) - lmax);
                lsum += e; lnum += e*gsc[sj];
            }
            #pragma unroll
            for(int m=32;m>=1;m>>=1){ lsum += __shfl_xor(lsum,m); lnum += __shfl_xor(lnum,m); }
            if(lane == 0) outF[nd] = lnum/(lsum + 1e-16f) + rc + bl[0];
        }
    }
}

// ---------------- launch ----------------
extern "C" void kernel_launch(void* const* d_in, const int* in_sizes, int n_in,
                              void* d_out, int out_size, void* d_ws, size_t ws_size,
                              hipStream_t stream) {
    const float* x   = (const float*)d_in[0];
    const int*   ei  = (const int*)d_in[1];
    const float* W1  = (const float*)d_in[2];
    const float* as1 = (const float*)d_in[3];
    const float* ad1 = (const float*)d_in[4];
    const float* b1  = (const float*)d_in[5];
    const float* W2  = (const float*)d_in[6];
    const float* as2 = (const float*)d_in[7];
    const float* ad2 = (const float*)d_in[8];
    const float* b2  = (const float*)d_in[9];
    const float* Wl  = (const float*)d_in[10];
    const float* bl  = (const float*)d_in[11];
    float* out = (float*)d_out;

    const int* srcp = ei;
    const int* dstp = ei + NE;

    char* w = (char*)d_ws;
    int*   edge_src = (int*)w;  w += (size_t)ET*4;      //  6.8 MB
    f16*   hb       = (f16*)w;  w += (size_t)NN*64*2;   // 12.8 MB
    f16*   t1b      = (f16*)w;  w += (size_t)NN*64*2;   // 12.8 MB
    int*   rowst    = (int*)w;  w += (size_t)NN*4;
    int*   deg      = (int*)w;  w += (size_t)NN*4;
    float* ssrc     = (float*)w; w += (size_t)NN*4;
    float* sdst     = (float*)w; w += (size_t)NN*4;
    float* gsc      = (float*)w; w += (size_t)NN*4;
    int*   bcnt     = (int*)w;  w += (size_t)NB*BST*4;
    int*   binbuf   = (int*)hb;     // aliases hb: dead before k_gemm<1> writes

    const int nbG = 782;                    // 3128 waves -> ~2 tiles each
    const int nbA = (NN/2 + 3)/4;           // 12500: 4 waves/block, 2 nodes/wave

    (void)hipMemsetAsync(bcnt, 0, (size_t)NB*BST*4, stream);
    k_bin  <<<NBIN, 256, 0, stream>>>(srcp, dstp, bcnt, binbuf);
    k_build<<<NB,   256, 0, stream>>>(bcnt, binbuf, edge_src, rowst, deg);

    // layer 1
    k_gemm<1,0><<<nbG, 256, 0, stream>>>((const void*)x, W1, as1, ad1,
                                         (const float*)nullptr, hb, ssrc, sdst,
                                         (float*)nullptr);
    k_agg1<<<nbA, 256, 0, stream>>>(rowst, deg, edge_src, ssrc, sdst, hb, b1, t1b);
    // layer 2 + final linear (scalar path: g = h.Wl, no h materialization)
    k_gemm<0,1><<<nbG, 256, 0, stream>>>((const void*)t1b, W2, as2, ad2, Wl,
                                         (f16*)nullptr, ssrc, sdst, gsc);
    k_agg2<<<nbA, 256, 0, stream>>>(rowst, deg, edge_src, ssrc, sdst, gsc,
                                    b2, Wl, bl, out);
}